// Round 4
// baseline (1042.416 us; speedup 1.0000x reference)
//
#include <hip/hip_runtime.h>
#include <hip/hip_bf16.h>
#include <math.h>

namespace {
constexpr int kNE   = 2048;
constexpr int kB    = 512;
constexpr int kDin  = 768;
constexpr int kD    = 512;
constexpr int kP    = 49;
constexpr int kNtot = kNE + kB;   // 2560
}

typedef __attribute__((ext_vector_type(8))) short bf16x8;
typedef __attribute__((ext_vector_type(4))) float f32x4;

__device__ inline ushort f2bf(float f) {  // RNE fp32 -> bf16 bits
  unsigned u = __float_as_uint(f);
  return (ushort)((u + 0x7fffu + ((u >> 16) & 1u)) >> 16);
}

// split v = hi + lo: hi = truncate-to-bf16 (exact), lo = rne(v - hi).
// |v - (hi + lo)| <= 2^-17 |v|  -> fp32-grade GEMM via 3 MFMA products.
__device__ inline void split4(const float4 v, ushort4& h, ushort4& l) {
  unsigned ux = __float_as_uint(v.x), uy = __float_as_uint(v.y),
           uz = __float_as_uint(v.z), uw = __float_as_uint(v.w);
  h.x = (ushort)(ux >> 16); h.y = (ushort)(uy >> 16);
  h.z = (ushort)(uz >> 16); h.w = (ushort)(uw >> 16);
  l.x = f2bf(v.x - __uint_as_float(ux & 0xFFFF0000u));
  l.y = f2bf(v.y - __uint_as_float(uy & 0xFFFF0000u));
  l.z = f2bf(v.z - __uint_as_float(uz & 0xFFFF0000u));
  l.w = f2bf(v.w - __uint_as_float(uw & 0xFFFF0000u));
}

// ---------------------------------------------------------------------------
// Compensated bf16x3 MFMA GEMM: C[M,N] = act(A[M,K] @ Bt[N,K]^T + bias).
// fp32 in/out; A,B split hi/lo bf16; D = Ah*Bh + Ah*Bl + Al*Bh (~2^-16 rel).
// 128x128 tile, 256 thr (4 waves = 2x2 of 64x64), BK=32, 16x16x32 MFMA.
// Requires M%128==0, N%128==0, K%32==0 (true at all call sites).
// ---------------------------------------------------------------------------
template <bool RELU>
__global__ __launch_bounds__(256) void gemm_bf16x3(const float* __restrict__ A,
                                                   const float* __restrict__ Bt,
                                                   const float* __restrict__ bias,
                                                   float* __restrict__ C,
                                                   int M, int N, int K) {
  __shared__ ushort Ah[128][40];   // +8 pad -> 80B stride (16B-aligned rows)
  __shared__ ushort Al[128][40];
  __shared__ ushort Bh[128][40];
  __shared__ ushort Bl[128][40];
  const int tid  = threadIdx.x;
  const int lane = tid & 63;
  const int w    = tid >> 6;
  const int wr   = (w >> 1) * 64;
  const int wc   = (w & 1) * 64;
  const int row0 = blockIdx.y * 128;
  const int col0 = blockIdx.x * 128;

  f32x4 acc[4][4] = {};

  const int fr = lane & 15;         // fragment row/col within 16
  const int fk = (lane >> 4) * 8;   // k sub-offset (consistent A/B)

  for (int k0 = 0; k0 < K; k0 += 32) {
#pragma unroll
    for (int i = 0; i < 4; ++i) {
      const int s  = tid + i * 256;   // 0..1023
      const int r  = s >> 3;          // 0..127
      const int f4 = s & 7;           // 0..7
      float4 va = *(const float4*)&A[(size_t)(row0 + r) * K + k0 + f4 * 4];
      ushort4 h, l; split4(va, h, l);
      *(ushort4*)&Ah[r][f4 * 4] = h;
      *(ushort4*)&Al[r][f4 * 4] = l;
      float4 vb = *(const float4*)&Bt[(size_t)(col0 + r) * K + k0 + f4 * 4];
      split4(vb, h, l);
      *(ushort4*)&Bh[r][f4 * 4] = h;
      *(ushort4*)&Bl[r][f4 * 4] = l;
    }
    __syncthreads();

    bf16x8 bh[4], bl[4];
#pragma unroll
    for (int n = 0; n < 4; ++n) {
      bh[n] = *(const bf16x8*)&Bh[wc + n * 16 + fr][fk];
      bl[n] = *(const bf16x8*)&Bl[wc + n * 16 + fr][fk];
    }
#pragma unroll
    for (int m = 0; m < 4; ++m) {
      bf16x8 ah = *(const bf16x8*)&Ah[wr + m * 16 + fr][fk];
      bf16x8 al = *(const bf16x8*)&Al[wr + m * 16 + fr][fk];
#pragma unroll
      for (int n = 0; n < 4; ++n) {
        acc[m][n] = __builtin_amdgcn_mfma_f32_16x16x32_bf16(ah, bh[n], acc[m][n], 0, 0, 0);
        acc[m][n] = __builtin_amdgcn_mfma_f32_16x16x32_bf16(al, bh[n], acc[m][n], 0, 0, 0);
        acc[m][n] = __builtin_amdgcn_mfma_f32_16x16x32_bf16(ah, bl[n], acc[m][n], 0, 0, 0);
      }
    }
    __syncthreads();
  }

  // epilogue: C/D layout col = lane&15, row = (lane>>4)*4 + j  [m89-verified]
  const int fq = lane >> 4;
#pragma unroll
  for (int n = 0; n < 4; ++n) {
    const int col = col0 + wc + n * 16 + fr;
    const float bv = bias ? bias[col] : 0.f;
#pragma unroll
    for (int m = 0; m < 4; ++m) {
      const int rbase = row0 + wr + m * 16 + fq * 4;
#pragma unroll
      for (int j = 0; j < 4; ++j) {
        float v = acc[m][n][j] + bv;
        if (RELU) v = fmaxf(v, 0.f);
        C[(size_t)(rbase + j) * N + col] = v;
      }
    }
  }
}

// ---------------------------------------------------------------------------
// Single-pass online-softmax attention pooling. Block per n, 256 threads;
// thread t owns dims {t, t+256, t+512}. Tokens read exactly once (385 MB).
// ---------------------------------------------------------------------------
__global__ __launch_bounds__(256) void attn_pool(
    const float* __restrict__ ent_toks, const float* __restrict__ men_toks,
    const float* __restrict__ u, float* __restrict__ ws768) {
  const int n = blockIdx.x;
  const float* toks = (n < kNE) ? ent_toks + (size_t)n * kP * kDin
                                : men_toks + (size_t)(n - kNE) * kP * kDin;
  const float* un = u + (size_t)n * kDin;
  const int t = threadIdx.x;
  const int lane = t & 63, wave = t >> 6;

  const float u0 = un[t], u1 = un[t + 256], u2 = un[t + 512];

  __shared__ float rs[2][4];
  float m = -INFINITY, l = 0.f, a0 = 0.f, a1 = 0.f, a2 = 0.f;
  const float scale = 0.044194173824159216f;  // 512^-0.5

  for (int p = 0; p < kP; ++p) {
    const float* tp = toks + (size_t)p * kDin;
    const float t0 = tp[t], t1 = tp[t + 256], t2 = tp[t + 512];
    float d = fmaf(t0, u0, fmaf(t1, u1, t2 * u2));
    for (int o = 32; o; o >>= 1) d += __shfl_xor(d, o);
    if (lane == 0) rs[p & 1][wave] = d;
    __syncthreads();
    const float s = (rs[p & 1][0] + rs[p & 1][1] + rs[p & 1][2] + rs[p & 1][3]) * scale;
    const float mn = fmaxf(m, s);
    const float c = __expf(m - mn);   // 0 on first iter
    const float e = __expf(s - mn);
    l = l * c + e;
    a0 = fmaf(a0, c, e * t0); a1 = fmaf(a1, c, e * t1); a2 = fmaf(a2, c, e * t2);
    m = mn;
  }
  const float inv = 1.f / l;
  float* wr = ws768 + (size_t)n * kDin;
  wr[t] = a0 * inv; wr[t + 256] = a1 * inv; wr[t + 512] = a2 * inv;
}

// ---------------------------------------------------------------------------
// Batched weight transpose (fp32): dst[C,R] = src[R,C]^T for 7 jobs.
// ---------------------------------------------------------------------------
struct TransJob { const float* src; float* dst; int R, C; };
struct TransArgs { TransJob j[7]; };

__global__ __launch_bounds__(256) void transpose7(TransArgs a) {
  const TransJob jb = a.j[blockIdx.z];
  const int r0 = blockIdx.y * 32, c0 = blockIdx.x * 32;
  if (r0 >= jb.R || c0 >= jb.C) return;
  __shared__ float tl[32][33];
  const int tx = threadIdx.x & 31, ty = threadIdx.x >> 5;  // 32x8
#pragma unroll
  for (int i = 0; i < 32; i += 8)
    tl[ty + i][tx] = jb.src[(size_t)(r0 + ty + i) * jb.C + c0 + tx];
  __syncthreads();
#pragma unroll
  for (int i = 0; i < 32; i += 8)
    jb.dst[(size_t)(c0 + ty + i) * jb.R + r0 + tx] = tl[tx][ty + i];
}

// ---------------------------------------------------------------------------
// Tiny GEMV: out[j] = sum_k vec[k] * W[k*N + j] + badd[j]
// ---------------------------------------------------------------------------
__global__ __launch_bounds__(64) void gemv_bias(const float* __restrict__ vec,
                                                const float* __restrict__ W,
                                                const float* __restrict__ badd,
                                                float* __restrict__ out, int K, int N) {
  const int j = blockIdx.x * 64 + threadIdx.x;
  float acc = 0.f;
  for (int k = 0; k < K; ++k) acc = fmaf(vec[k], W[(size_t)k * N + j], acc);
  out[j] = acc + badd[j];
}

// ---------------------------------------------------------------------------
__global__ __launch_bounds__(64) void moe_gate(
    const float* __restrict__ txt, const float* __restrict__ img,
    const float* __restrict__ gw, const float* __restrict__ gb,
    float* __restrict__ gate2) {
  const int n = blockIdx.x;
  const int lane = threadIdx.x;
  float a0 = 0.f, a1 = 0.f;
  for (int k = lane; k < kD; k += 64) {
    const float t = txt[(size_t)n * kD + k];
    a0 = fmaf(t, gw[k * 2 + 0], a0);
    a1 = fmaf(t, gw[k * 2 + 1], a1);
    const float im = img[(size_t)n * kD + k];
    a0 = fmaf(im, gw[(kD + k) * 2 + 0], a0);
    a1 = fmaf(im, gw[(kD + k) * 2 + 1], a1);
  }
  for (int o = 32; o; o >>= 1) { a0 += __shfl_xor(a0, o); a1 += __shfl_xor(a1, o); }
  if (lane == 0) {
    const float l0 = a0 + gb[0], l1 = a1 + gb[1];
    const float m = fmaxf(l0, l1);
    const float e0 = __expf(l0 - m), e1 = __expf(l1 - m);
    const float inv = 1.f / (e0 + e1);
    gate2[n * 2 + 0] = e0 * inv;
    gate2[n * 2 + 1] = e1 * inv;
  }
}

__global__ __launch_bounds__(256) void finalize_ln(
    const float* __restrict__ cls_p, const float* __restrict__ et,
    const float* __restrict__ ei, const float* __restrict__ gate2,
    const float* __restrict__ gfw, const float* __restrict__ gfb,
    const float* __restrict__ lng, const float* __restrict__ lnb,
    float* __restrict__ outp) {
  const int n = blockIdx.x;
  const int t = threadIdx.x;
  const int lane = t & 63, wave = t >> 6;
  const float* cp = cls_p + (size_t)n * kD;
  const float c0 = cp[t], c1 = cp[t + 256];

  float d = fmaf(c0, gfw[t], c1 * gfw[t + 256]);
  for (int o = 32; o; o >>= 1) d += __shfl_xor(d, o);
  __shared__ float rsh[4];
  __shared__ float gtb;
  if (lane == 0) rsh[wave] = d;
  __syncthreads();
  if (t == 0) gtb = tanhf(rsh[0] + rsh[1] + rsh[2] + rsh[3] + gfb[0]);
  __syncthreads();
  const float gt = gtb;
  const float g0 = gate2[n * 2 + 0], g1 = gate2[n * 2 + 1];

  const size_t base = (size_t)n * kD;
  const float y0 = c0 * gt + g0 * et[base + t]       + g1 * ei[base + t];
  const float y1 = c1 * gt + g0 * et[base + 256 + t] + g1 * ei[base + 256 + t];

  float s = y0 + y1, ss = fmaf(y0, y0, y1 * y1);
  for (int o = 32; o; o >>= 1) { s += __shfl_xor(s, o); ss += __shfl_xor(ss, o); }
  __shared__ float rsum[4], rssq[4];
  __shared__ float mb, ivb;
  if (lane == 0) { rsum[wave] = s; rssq[wave] = ss; }
  __syncthreads();
  if (t == 0) {
    const float S  = rsum[0] + rsum[1] + rsum[2] + rsum[3];
    const float SS = rssq[0] + rssq[1] + rssq[2] + rssq[3];
    const float mm = S / (float)kD;
    const float v  = SS / (float)kD - mm * mm;
    mb = mm; ivb = rsqrtf(v + 1e-5f);
  }
  __syncthreads();
  const float mm = mb, iv = ivb;
  outp[base + t]       = (y0 - mm) * iv * lng[t] + lnb[t];
  outp[base + 256 + t] = (y1 - mm) * iv * lng[t + 256] + lnb[t + 256];
}

// ---------------------------------------------------------------------------
extern "C" void kernel_launch(void* const* d_in, const int* in_sizes, int n_in,
                              void* d_out, int out_size, void* d_ws, size_t ws_size,
                              hipStream_t stream) {
  const float* ent_cls  = (const float*)d_in[0];
  const float* ent_tok  = (const float*)d_in[1];
  const float* men_cls  = (const float*)d_in[2];
  const float* men_tok  = (const float*)d_in[3];
  const float* text_w   = (const float*)d_in[4];
  const float* text_b   = (const float*)d_in[5];
  const float* img_w    = (const float*)d_in[6];
  const float* img_b    = (const float*)d_in[7];
  const float* gate_w   = (const float*)d_in[8];
  const float* gate_b   = (const float*)d_in[9];
  const float* ln_g     = (const float*)d_in[10];
  const float* ln_b     = (const float*)d_in[11];
  const float* match_w  = (const float*)d_in[12];
  const float* match_b  = (const float*)d_in[13];
  // d_in[14..18] (mh_query, mh_wq, mh_bq, mh_wk, mh_bk) provably unused
  const float* mh_wv    = (const float*)d_in[19];
  const float* mh_bv    = (const float*)d_in[20];
  const float* mh_wo    = (const float*)d_in[21];
  const float* mh_bo    = (const float*)d_in[22];
  const float* moe_gw   = (const float*)d_in[23];
  const float* moe_gb   = (const float*)d_in[24];
  const float* moe_tw1  = (const float*)d_in[25];
  const float* moe_tb1  = (const float*)d_in[26];
  const float* moe_tw2  = (const float*)d_in[27];
  const float* moe_tb2  = (const float*)d_in[28];
  const float* moe_iw1  = (const float*)d_in[29];
  const float* moe_ib1  = (const float*)d_in[30];
  const float* moe_iw2  = (const float*)d_in[31];
  const float* moe_ib2  = (const float*)d_in[32];

  float* w = (float*)d_ws;
  size_t o = 0;
  auto alloc = [&](size_t nf) { size_t r = o; o += (nf + 127) & ~(size_t)127; return r; };
  const size_t o_clsp   = alloc((size_t)kNtot * kD);
  const size_t o_u_ht   = alloc((size_t)kNtot * kDin);  // u, reused as h_t
  const size_t o_ws_hi  = alloc((size_t)kNtot * kDin);  // ws768, reused as h_i
  const size_t o_txt    = alloc((size_t)kNtot * kD);
  const size_t o_img    = alloc((size_t)kNtot * kD);
  const size_t o_et     = alloc((size_t)kNtot * kD);
  const size_t o_ei     = alloc((size_t)kNtot * kD);
  const size_t o_ctx    = alloc((size_t)kNtot * kD);
  const size_t o_WcombT = alloc((size_t)kD * kDin);     // [512,768]
  const size_t o_U      = alloc((size_t)kD * kD);
  const size_t o_WimgT  = alloc((size_t)kD * kD);
  const size_t o_bcomb  = alloc(kD);
  const size_t o_bt1    = alloc(kD);
  const size_t o_bimg   = alloc(kD);
  const size_t o_gate   = alloc((size_t)kNtot * 2);
  const size_t o_textWT = alloc((size_t)kD * kDin);     // [512,768]
  const size_t o_matchWT= alloc((size_t)kD * kD);
  const size_t o_mhWoT  = alloc((size_t)kD * kD);
  const size_t o_tw1T   = alloc((size_t)kD * kD);
  const size_t o_tw2T   = alloc((size_t)kD * kD);
  const size_t o_iw1T   = alloc((size_t)kD * kD);
  const size_t o_iw2T   = alloc((size_t)kD * kD);
  (void)ws_size; (void)n_in; (void)in_sizes; (void)out_size;

  auto G = [](int M, int N) { return dim3((unsigned)(N / 128), (unsigned)(M / 128)); };

  // 0. transpose all [K,N] weights -> [N,K]
  TransArgs ta;
  ta.j[0] = { text_w,  w + o_textWT,  kDin, kD };
  ta.j[1] = { match_w, w + o_matchWT, kD,   kD };
  ta.j[2] = { mh_wo,   w + o_mhWoT,   kD,   kD };
  ta.j[3] = { moe_tw1, w + o_tw1T,    kD,   kD };
  ta.j[4] = { moe_tw2, w + o_tw2T,    kD,   kD };
  ta.j[5] = { moe_iw1, w + o_iw1T,    kD,   kD };
  ta.j[6] = { moe_iw2, w + o_iw2T,    kD,   kD };
  hipLaunchKernelGGL(transpose7, dim3(16, 24, 7), 256, 0, stream, ta);

  // 1. cls_p = cls @ text_w + text_b
  hipLaunchKernelGGL((gemm_bf16x3<false>), G(kNE, kD), 256, 0, stream,
                     ent_cls, w + o_textWT, text_b, w + o_clsp, kNE, kD, kDin);
  hipLaunchKernelGGL((gemm_bf16x3<false>), G(kB, kD), 256, 0, stream,
                     men_cls, w + o_textWT, text_b, w + o_clsp + (size_t)kNE * kD, kB, kD, kDin);

  // 2. u = cls_p @ img_w^T  (Bt = img_w as stored [768,512])
  hipLaunchKernelGGL((gemm_bf16x3<false>), G(kNtot, kDin), 256, 0, stream,
                     w + o_clsp, img_w, (const float*)nullptr, w + o_u_ht, kNtot, kDin, kD);

  // 3. single-pass softmax pooling -> ws768
  hipLaunchKernelGGL(attn_pool, dim3(kNtot), 256, 0, stream,
                     ent_tok, men_tok, w + o_u_ht, w + o_ws_hi);

  // 4. WcombT = (img_w @ match_w)^T = G(match_wT, img_w)   [512,768]
  hipLaunchKernelGGL((gemm_bf16x3<false>), G(kD, kDin), 256, 0, stream,
                     w + o_matchWT, img_w, (const float*)nullptr, w + o_WcombT, kD, kDin, kD);
  // bcomb = img_b @ match_w + match_b   (img_b is [512]; K = kD)
  hipLaunchKernelGGL(gemv_bias, dim3(kD / 64), 64, 0, stream,
                     img_b, match_w, match_b, w + o_bcomb, kD, kD);

  // 5. txt = ws768 @ Wcomb + bcomb
  hipLaunchKernelGGL((gemm_bf16x3<false>), G(kNtot, kD), 256, 0, stream,
                     w + o_ws_hi, w + o_WcombT, w + o_bcomb, w + o_txt, kNtot, kD, kDin);

  // 6. WimgT = (match_w@wv@wo)^T: U = G(mh_woT, mh_wv); WimgT = G(U, match_w)
  hipLaunchKernelGGL((gemm_bf16x3<false>), G(kD, kD), 256, 0, stream,
                     w + o_mhWoT, mh_wv, (const float*)nullptr, w + o_U, kD, kD, kD);
  hipLaunchKernelGGL((gemm_bf16x3<false>), G(kD, kD), 256, 0, stream,
                     w + o_U, match_w, (const float*)nullptr, w + o_WimgT, kD, kD, kD);
  hipLaunchKernelGGL(gemv_bias, dim3(kD / 64), 64, 0, stream,
                     match_b, mh_wv, mh_bv, w + o_bt1, kD, kD);
  hipLaunchKernelGGL(gemv_bias, dim3(kD / 64), 64, 0, stream,
                     w + o_bt1, mh_wo, mh_bo, w + o_bimg, kD, kD);
  hipLaunchKernelGGL((gemm_bf16x3<false>), G(kNtot, kD), 256, 0, stream,
                     w + o_clsp, w + o_WimgT, w + o_bimg, w + o_img, kNtot, kD, kD);

  // 7. MoE gate
  hipLaunchKernelGGL(moe_gate, dim3(kNtot), 64, 0, stream,
                     w + o_txt, w + o_img, moe_gw, moe_gb, w + o_gate);

  // 8. experts
  hipLaunchKernelGGL((gemm_bf16x3<true>), G(kNtot, kD), 256, 0, stream,
                     w + o_txt, w + o_tw1T, moe_tb1, w + o_u_ht, kNtot, kD, kD);
  hipLaunchKernelGGL((gemm_bf16x3<false>), G(kNtot, kD), 256, 0, stream,
                     w + o_u_ht, w + o_tw2T, moe_tb2, w + o_et, kNtot, kD, kD);
  hipLaunchKernelGGL((gemm_bf16x3<true>), G(kNtot, kD), 256, 0, stream,
                     w + o_img, w + o_iw1T, moe_ib1, w + o_ws_hi, kNtot, kD, kD);
  hipLaunchKernelGGL((gemm_bf16x3<false>), G(kNtot, kD), 256, 0, stream,
                     w + o_ws_hi, w + o_iw2T, moe_ib2, w + o_ei, kNtot, kD, kD);

  // 9. finalize (tanh-gate + MoE combine + LN) -> ctx
  hipLaunchKernelGGL(finalize_ln, dim3(kNtot), 256, 0, stream,
                     w + o_clsp, w + o_et, w + o_ei, w + o_gate,
                     gate_w, gate_b, ln_g, ln_b, w + o_ctx);

  // 10. out = m_ctx @ e_ctx^T  (Bt = e_ctx as stored)
  hipLaunchKernelGGL((gemm_bf16x3<false>), G(kB, kNE), 256, 0, stream,
                     w + o_ctx + (size_t)kNE * kD, w + o_ctx, (const float*)nullptr,
                     (float*)d_out, kB, kNE, kD);
}

// Round 5
// 576.123 us; speedup vs baseline: 1.8094x; 1.8094x over previous
//
#include <hip/hip_runtime.h>
#include <hip/hip_bf16.h>
#include <math.h>

namespace {
constexpr int kNE   = 2048;
constexpr int kB    = 512;
constexpr int kDin  = 768;
constexpr int kD    = 512;
constexpr int kP    = 49;
constexpr int kNtot = kNE + kB;   // 2560
}

typedef __attribute__((ext_vector_type(8))) short bf16x8;
typedef __attribute__((ext_vector_type(4))) float f32x4;

__device__ inline ushort f2bf(float f) {  // RNE fp32 -> bf16 bits
  unsigned u = __float_as_uint(f);
  return (ushort)((u + 0x7fffu + ((u >> 16) & 1u)) >> 16);
}

// split v = hi + lo: hi = truncate-to-bf16 (exact), lo = rne(v - hi).
// |v - (hi + lo)| <= 2^-17 |v|  -> fp32-grade GEMM via 3 MFMA products.
__device__ inline void split4(const float4 v, ushort4& h, ushort4& l) {
  unsigned ux = __float_as_uint(v.x), uy = __float_as_uint(v.y),
           uz = __float_as_uint(v.z), uw = __float_as_uint(v.w);
  h.x = (ushort)(ux >> 16); h.y = (ushort)(uy >> 16);
  h.z = (ushort)(uz >> 16); h.w = (ushort)(uw >> 16);
  l.x = f2bf(v.x - __uint_as_float(ux & 0xFFFF0000u));
  l.y = f2bf(v.y - __uint_as_float(uy & 0xFFFF0000u));
  l.z = f2bf(v.z - __uint_as_float(uz & 0xFFFF0000u));
  l.w = f2bf(v.w - __uint_as_float(uw & 0xFFFF0000u));
}

// ---------------------------------------------------------------------------
// Compensated bf16x3 MFMA GEMM: C[M,N] = act(A[M,K] @ Bt[N,K]^T + bias).
// fp32 in/out; A,B split hi/lo bf16; D = Ah*Bh + Ah*Bl + Al*Bh (~2^-16 rel).
// 128x128 tile, 256 thr (4 waves = 2x2 of 64x64), BK=32, 16x16x32 MFMA.
// Requires M%128==0, N%128==0, K%32==0 (true at all call sites).
// ---------------------------------------------------------------------------
template <bool RELU>
__global__ __launch_bounds__(256) void gemm_bf16x3(const float* __restrict__ A,
                                                   const float* __restrict__ Bt,
                                                   const float* __restrict__ bias,
                                                   float* __restrict__ C,
                                                   int M, int N, int K) {
  __shared__ ushort Ah[128][40];   // +8 pad -> 80B stride (16B-aligned rows)
  __shared__ ushort Al[128][40];
  __shared__ ushort Bh[128][40];
  __shared__ ushort Bl[128][40];
  const int tid  = threadIdx.x;
  const int lane = tid & 63;
  const int w    = tid >> 6;
  const int wr   = (w >> 1) * 64;
  const int wc   = (w & 1) * 64;
  const int row0 = blockIdx.y * 128;
  const int col0 = blockIdx.x * 128;

  f32x4 acc[4][4] = {};

  const int fr = lane & 15;         // fragment row/col within 16
  const int fk = (lane >> 4) * 8;   // k sub-offset (consistent A/B)

  for (int k0 = 0; k0 < K; k0 += 32) {
#pragma unroll
    for (int i = 0; i < 4; ++i) {
      const int s  = tid + i * 256;   // 0..1023
      const int r  = s >> 3;          // 0..127
      const int f4 = s & 7;           // 0..7
      float4 va = *(const float4*)&A[(size_t)(row0 + r) * K + k0 + f4 * 4];
      ushort4 h, l; split4(va, h, l);
      *(ushort4*)&Ah[r][f4 * 4] = h;
      *(ushort4*)&Al[r][f4 * 4] = l;
      float4 vb = *(const float4*)&Bt[(size_t)(col0 + r) * K + k0 + f4 * 4];
      split4(vb, h, l);
      *(ushort4*)&Bh[r][f4 * 4] = h;
      *(ushort4*)&Bl[r][f4 * 4] = l;
    }
    __syncthreads();

    bf16x8 bh[4], bl[4];
#pragma unroll
    for (int n = 0; n < 4; ++n) {
      bh[n] = *(const bf16x8*)&Bh[wc + n * 16 + fr][fk];
      bl[n] = *(const bf16x8*)&Bl[wc + n * 16 + fr][fk];
    }
#pragma unroll
    for (int m = 0; m < 4; ++m) {
      bf16x8 ah = *(const bf16x8*)&Ah[wr + m * 16 + fr][fk];
      bf16x8 al = *(const bf16x8*)&Al[wr + m * 16 + fr][fk];
#pragma unroll
      for (int n = 0; n < 4; ++n) {
        acc[m][n] = __builtin_amdgcn_mfma_f32_16x16x32_bf16(ah, bh[n], acc[m][n], 0, 0, 0);
        acc[m][n] = __builtin_amdgcn_mfma_f32_16x16x32_bf16(al, bh[n], acc[m][n], 0, 0, 0);
        acc[m][n] = __builtin_amdgcn_mfma_f32_16x16x32_bf16(ah, bl[n], acc[m][n], 0, 0, 0);
      }
    }
    __syncthreads();
  }

  // epilogue: C/D layout col = lane&15, row = (lane>>4)*4 + j  [m89-verified]
  const int fq = lane >> 4;
#pragma unroll
  for (int n = 0; n < 4; ++n) {
    const int col = col0 + wc + n * 16 + fr;
    const float bv = bias ? bias[col] : 0.f;
#pragma unroll
    for (int m = 0; m < 4; ++m) {
      const int rbase = row0 + wr + m * 16 + fq * 4;
#pragma unroll
      for (int j = 0; j < 4; ++j) {
        float v = acc[m][n][j] + bv;
        if (RELU) v = fmaxf(v, 0.f);
        C[(size_t)(rbase + j) * N + col] = v;
      }
    }
  }
}

// ---------------------------------------------------------------------------
// Single-pass online-softmax attention pooling. Block per n, 256 threads;
// thread t owns dims {t, t+256, t+512}. Tokens read exactly once (385 MB).
// ---------------------------------------------------------------------------
__global__ __launch_bounds__(256) void attn_pool(
    const float* __restrict__ ent_toks, const float* __restrict__ men_toks,
    const float* __restrict__ u, float* __restrict__ ws768) {
  const int n = blockIdx.x;
  const float* toks = (n < kNE) ? ent_toks + (size_t)n * kP * kDin
                                : men_toks + (size_t)(n - kNE) * kP * kDin;
  const float* un = u + (size_t)n * kDin;
  const int t = threadIdx.x;
  const int lane = t & 63, wave = t >> 6;

  const float u0 = un[t], u1 = un[t + 256], u2 = un[t + 512];

  __shared__ float rs[2][4];
  float m = -INFINITY, l = 0.f, a0 = 0.f, a1 = 0.f, a2 = 0.f;
  const float scale = 0.044194173824159216f;  // 512^-0.5

  for (int p = 0; p < kP; ++p) {
    const float* tp = toks + (size_t)p * kDin;
    const float t0 = tp[t], t1 = tp[t + 256], t2 = tp[t + 512];
    float d = fmaf(t0, u0, fmaf(t1, u1, t2 * u2));
    for (int o = 32; o; o >>= 1) d += __shfl_xor(d, o);
    if (lane == 0) rs[p & 1][wave] = d;
    __syncthreads();
    const float s = (rs[p & 1][0] + rs[p & 1][1] + rs[p & 1][2] + rs[p & 1][3]) * scale;
    const float mn = fmaxf(m, s);
    const float c = __expf(m - mn);   // 0 on first iter
    const float e = __expf(s - mn);
    l = l * c + e;
    a0 = fmaf(a0, c, e * t0); a1 = fmaf(a1, c, e * t1); a2 = fmaf(a2, c, e * t2);
    m = mn;
  }
  const float inv = 1.f / l;
  float* wr = ws768 + (size_t)n * kDin;
  wr[t] = a0 * inv; wr[t + 256] = a1 * inv; wr[t + 512] = a2 * inv;
}

// ---------------------------------------------------------------------------
// Batched weight transpose (fp32): dst[C,R] = src[R,C]^T for 7 jobs.
// ---------------------------------------------------------------------------
struct TransJob { const float* src; float* dst; int R, C; };
struct TransArgs { TransJob j[7]; };

__global__ __launch_bounds__(256) void transpose7(TransArgs a) {
  const TransJob jb = a.j[blockIdx.z];
  const int r0 = blockIdx.y * 32, c0 = blockIdx.x * 32;
  if (r0 >= jb.R || c0 >= jb.C) return;
  __shared__ float tl[32][33];
  const int tx = threadIdx.x & 31, ty = threadIdx.x >> 5;  // 32x8
#pragma unroll
  for (int i = 0; i < 32; i += 8)
    tl[ty + i][tx] = jb.src[(size_t)(r0 + ty + i) * jb.C + c0 + tx];
  __syncthreads();
#pragma unroll
  for (int i = 0; i < 32; i += 8)
    jb.dst[(size_t)(c0 + ty + i) * jb.R + r0 + tx] = tl[tx][ty + i];
}

// ---------------------------------------------------------------------------
// Parallel GEMV: out[j] = sum_k vec[k]*W[k*N+j] + badd[j].
// One block per output column j: 256 threads strided over K, shuffle+LDS
// reduce. (The old serial version was 195 us/launch: 8 wg, 512-deep
// dependent-load chain. This is ~1000x more parallel.)
// ---------------------------------------------------------------------------
__global__ __launch_bounds__(256) void gemv_bias(const float* __restrict__ vec,
                                                 const float* __restrict__ W,
                                                 const float* __restrict__ badd,
                                                 float* __restrict__ out, int K, int N) {
  const int j = blockIdx.x;
  const int t = threadIdx.x;
  float acc = 0.f;
  for (int k = t; k < K; k += 256) acc = fmaf(vec[k], W[(size_t)k * N + j], acc);
  for (int o = 32; o; o >>= 1) acc += __shfl_xor(acc, o);
  __shared__ float r[4];
  if ((t & 63) == 0) r[t >> 6] = acc;
  __syncthreads();
  if (t == 0) out[j] = r[0] + r[1] + r[2] + r[3] + badd[j];
}

// ---------------------------------------------------------------------------
__global__ __launch_bounds__(64) void moe_gate(
    const float* __restrict__ txt, const float* __restrict__ img,
    const float* __restrict__ gw, const float* __restrict__ gb,
    float* __restrict__ gate2) {
  const int n = blockIdx.x;
  const int lane = threadIdx.x;
  float a0 = 0.f, a1 = 0.f;
  for (int k = lane; k < kD; k += 64) {
    const float t = txt[(size_t)n * kD + k];
    a0 = fmaf(t, gw[k * 2 + 0], a0);
    a1 = fmaf(t, gw[k * 2 + 1], a1);
    const float im = img[(size_t)n * kD + k];
    a0 = fmaf(im, gw[(kD + k) * 2 + 0], a0);
    a1 = fmaf(im, gw[(kD + k) * 2 + 1], a1);
  }
  for (int o = 32; o; o >>= 1) { a0 += __shfl_xor(a0, o); a1 += __shfl_xor(a1, o); }
  if (lane == 0) {
    const float l0 = a0 + gb[0], l1 = a1 + gb[1];
    const float m = fmaxf(l0, l1);
    const float e0 = __expf(l0 - m), e1 = __expf(l1 - m);
    const float inv = 1.f / (e0 + e1);
    gate2[n * 2 + 0] = e0 * inv;
    gate2[n * 2 + 1] = e1 * inv;
  }
}

__global__ __launch_bounds__(256) void finalize_ln(
    const float* __restrict__ cls_p, const float* __restrict__ et,
    const float* __restrict__ ei, const float* __restrict__ gate2,
    const float* __restrict__ gfw, const float* __restrict__ gfb,
    const float* __restrict__ lng, const float* __restrict__ lnb,
    float* __restrict__ outp) {
  const int n = blockIdx.x;
  const int t = threadIdx.x;
  const int lane = t & 63, wave = t >> 6;
  const float* cp = cls_p + (size_t)n * kD;
  const float c0 = cp[t], c1 = cp[t + 256];

  float d = fmaf(c0, gfw[t], c1 * gfw[t + 256]);
  for (int o = 32; o; o >>= 1) d += __shfl_xor(d, o);
  __shared__ float rsh[4];
  __shared__ float gtb;
  if (lane == 0) rsh[wave] = d;
  __syncthreads();
  if (t == 0) gtb = tanhf(rsh[0] + rsh[1] + rsh[2] + rsh[3] + gfb[0]);
  __syncthreads();
  const float gt = gtb;
  const float g0 = gate2[n * 2 + 0], g1 = gate2[n * 2 + 1];

  const size_t base = (size_t)n * kD;
  const float y0 = c0 * gt + g0 * et[base + t]       + g1 * ei[base + t];
  const float y1 = c1 * gt + g0 * et[base + 256 + t] + g1 * ei[base + 256 + t];

  float s = y0 + y1, ss = fmaf(y0, y0, y1 * y1);
  for (int o = 32; o; o >>= 1) { s += __shfl_xor(s, o); ss += __shfl_xor(ss, o); }
  __shared__ float rsum[4], rssq[4];
  __shared__ float mb, ivb;
  if (lane == 0) { rsum[wave] = s; rssq[wave] = ss; }
  __syncthreads();
  if (t == 0) {
    const float S  = rsum[0] + rsum[1] + rsum[2] + rsum[3];
    const float SS = rssq[0] + rssq[1] + rssq[2] + rssq[3];
    const float mm = S / (float)kD;
    const float v  = SS / (float)kD - mm * mm;
    mb = mm; ivb = rsqrtf(v + 1e-5f);
  }
  __syncthreads();
  const float mm = mb, iv = ivb;
  outp[base + t]       = (y0 - mm) * iv * lng[t] + lnb[t];
  outp[base + 256 + t] = (y1 - mm) * iv * lng[t + 256] + lnb[t + 256];
}

// ---------------------------------------------------------------------------
extern "C" void kernel_launch(void* const* d_in, const int* in_sizes, int n_in,
                              void* d_out, int out_size, void* d_ws, size_t ws_size,
                              hipStream_t stream) {
  const float* ent_cls  = (const float*)d_in[0];
  const float* ent_tok  = (const float*)d_in[1];
  const float* men_cls  = (const float*)d_in[2];
  const float* men_tok  = (const float*)d_in[3];
  const float* text_w   = (const float*)d_in[4];
  const float* text_b   = (const float*)d_in[5];
  const float* img_w    = (const float*)d_in[6];
  const float* img_b    = (const float*)d_in[7];
  const float* gate_w   = (const float*)d_in[8];
  const float* gate_b   = (const float*)d_in[9];
  const float* ln_g     = (const float*)d_in[10];
  const float* ln_b     = (const float*)d_in[11];
  const float* match_w  = (const float*)d_in[12];
  const float* match_b  = (const float*)d_in[13];
  // d_in[14..18] (mh_query, mh_wq, mh_bq, mh_wk, mh_bk) provably unused
  const float* mh_wv    = (const float*)d_in[19];
  const float* mh_bv    = (const float*)d_in[20];
  const float* mh_wo    = (const float*)d_in[21];
  const float* mh_bo    = (const float*)d_in[22];
  const float* moe_gw   = (const float*)d_in[23];
  const float* moe_gb   = (const float*)d_in[24];
  const float* moe_tw1  = (const float*)d_in[25];
  const float* moe_tb1  = (const float*)d_in[26];
  const float* moe_tw2  = (const float*)d_in[27];
  const float* moe_tb2  = (const float*)d_in[28];
  const float* moe_iw1  = (const float*)d_in[29];
  const float* moe_ib1  = (const float*)d_in[30];
  const float* moe_iw2  = (const float*)d_in[31];
  const float* moe_ib2  = (const float*)d_in[32];

  float* w = (float*)d_ws;
  size_t o = 0;
  auto alloc = [&](size_t nf) { size_t r = o; o += (nf + 127) & ~(size_t)127; return r; };
  const size_t o_clsp   = alloc((size_t)kNtot * kD);
  const size_t o_u_ht   = alloc((size_t)kNtot * kDin);  // u, reused as h_t
  const size_t o_ws_hi  = alloc((size_t)kNtot * kDin);  // ws768, reused as h_i
  const size_t o_txt    = alloc((size_t)kNtot * kD);
  const size_t o_img    = alloc((size_t)kNtot * kD);
  const size_t o_et     = alloc((size_t)kNtot * kD);
  const size_t o_ei     = alloc((size_t)kNtot * kD);
  const size_t o_ctx    = alloc((size_t)kNtot * kD);
  const size_t o_WcombT = alloc((size_t)kD * kDin);     // [512,768]
  const size_t o_U      = alloc((size_t)kD * kD);
  const size_t o_WimgT  = alloc((size_t)kD * kD);
  const size_t o_bcomb  = alloc(kD);
  const size_t o_bt1    = alloc(kD);
  const size_t o_bimg   = alloc(kD);
  const size_t o_gate   = alloc((size_t)kNtot * 2);
  const size_t o_textWT = alloc((size_t)kD * kDin);     // [512,768]
  const size_t o_matchWT= alloc((size_t)kD * kD);
  const size_t o_mhWoT  = alloc((size_t)kD * kD);
  const size_t o_tw1T   = alloc((size_t)kD * kD);
  const size_t o_tw2T   = alloc((size_t)kD * kD);
  const size_t o_iw1T   = alloc((size_t)kD * kD);
  const size_t o_iw2T   = alloc((size_t)kD * kD);
  (void)ws_size; (void)n_in; (void)in_sizes; (void)out_size;

  auto G = [](int M, int N) { return dim3((unsigned)(N / 128), (unsigned)(M / 128)); };

  // 0. transpose all [K,N] weights -> [N,K]
  TransArgs ta;
  ta.j[0] = { text_w,  w + o_textWT,  kDin, kD };
  ta.j[1] = { match_w, w + o_matchWT, kD,   kD };
  ta.j[2] = { mh_wo,   w + o_mhWoT,   kD,   kD };
  ta.j[3] = { moe_tw1, w + o_tw1T,    kD,   kD };
  ta.j[4] = { moe_tw2, w + o_tw2T,    kD,   kD };
  ta.j[5] = { moe_iw1, w + o_iw1T,    kD,   kD };
  ta.j[6] = { moe_iw2, w + o_iw2T,    kD,   kD };
  hipLaunchKernelGGL(transpose7, dim3(16, 24, 7), 256, 0, stream, ta);

  // 1. cls_p = cls @ text_w + text_b
  hipLaunchKernelGGL((gemm_bf16x3<false>), G(kNE, kD), 256, 0, stream,
                     ent_cls, w + o_textWT, text_b, w + o_clsp, kNE, kD, kDin);
  hipLaunchKernelGGL((gemm_bf16x3<false>), G(kB, kD), 256, 0, stream,
                     men_cls, w + o_textWT, text_b, w + o_clsp + (size_t)kNE * kD, kB, kD, kDin);

  // 2. u = cls_p @ img_w^T  (Bt = img_w as stored [768,512])
  hipLaunchKernelGGL((gemm_bf16x3<false>), G(kNtot, kDin), 256, 0, stream,
                     w + o_clsp, img_w, (const float*)nullptr, w + o_u_ht, kNtot, kDin, kD);

  // 3. single-pass softmax pooling -> ws768
  hipLaunchKernelGGL(attn_pool, dim3(kNtot), 256, 0, stream,
                     ent_tok, men_tok, w + o_u_ht, w + o_ws_hi);

  // 4. WcombT = (img_w @ match_w)^T = G(match_wT, img_w)   [512,768]
  hipLaunchKernelGGL((gemm_bf16x3<false>), G(kD, kDin), 256, 0, stream,
                     w + o_matchWT, img_w, (const float*)nullptr, w + o_WcombT, kD, kDin, kD);
  // bcomb = img_b @ match_w + match_b   (img_b is [512]; K = kD)
  hipLaunchKernelGGL(gemv_bias, dim3(kD), 256, 0, stream,
                     img_b, match_w, match_b, w + o_bcomb, kD, kD);

  // 5. txt = ws768 @ Wcomb + bcomb
  hipLaunchKernelGGL((gemm_bf16x3<false>), G(kNtot, kD), 256, 0, stream,
                     w + o_ws_hi, w + o_WcombT, w + o_bcomb, w + o_txt, kNtot, kD, kDin);

  // 6. WimgT = (match_w@wv@wo)^T: U = G(mh_woT, mh_wv); WimgT = G(U, match_w)
  hipLaunchKernelGGL((gemm_bf16x3<false>), G(kD, kD), 256, 0, stream,
                     w + o_mhWoT, mh_wv, (const float*)nullptr, w + o_U, kD, kD, kD);
  hipLaunchKernelGGL((gemm_bf16x3<false>), G(kD, kD), 256, 0, stream,
                     w + o_U, match_w, (const float*)nullptr, w + o_WimgT, kD, kD, kD);
  hipLaunchKernelGGL(gemv_bias, dim3(kD), 256, 0, stream,
                     match_b, mh_wv, mh_bv, w + o_bt1, kD, kD);
  hipLaunchKernelGGL(gemv_bias, dim3(kD), 256, 0, stream,
                     w + o_bt1, mh_wo, mh_bo, w + o_bimg, kD, kD);
  hipLaunchKernelGGL((gemm_bf16x3<false>), G(kNtot, kD), 256, 0, stream,
                     w + o_clsp, w + o_WimgT, w + o_bimg, w + o_img, kNtot, kD, kD);

  // 7. MoE gate
  hipLaunchKernelGGL(moe_gate, dim3(kNtot), 64, 0, stream,
                     w + o_txt, w + o_img, moe_gw, moe_gb, w + o_gate);

  // 8. experts
  hipLaunchKernelGGL((gemm_bf16x3<true>), G(kNtot, kD), 256, 0, stream,
                     w + o_txt, w + o_tw1T, moe_tb1, w + o_u_ht, kNtot, kD, kD);
  hipLaunchKernelGGL((gemm_bf16x3<false>), G(kNtot, kD), 256, 0, stream,
                     w + o_u_ht, w + o_tw2T, moe_tb2, w + o_et, kNtot, kD, kD);
  hipLaunchKernelGGL((gemm_bf16x3<true>), G(kNtot, kD), 256, 0, stream,
                     w + o_img, w + o_iw1T, moe_ib1, w + o_ws_hi, kNtot, kD, kD);
  hipLaunchKernelGGL((gemm_bf16x3<false>), G(kNtot, kD), 256, 0, stream,
                     w + o_ws_hi, w + o_iw2T, moe_ib2, w + o_ei, kNtot, kD, kD);

  // 9. finalize (tanh-gate + MoE combine + LN) -> ctx
  hipLaunchKernelGGL(finalize_ln, dim3(kNtot), 256, 0, stream,
                     w + o_clsp, w + o_et, w + o_ei, w + o_gate,
                     gate_w, gate_b, ln_g, ln_b, w + o_ctx);

  // 10. out = m_ctx @ e_ctx^T  (Bt = e_ctx as stored)
  hipLaunchKernelGGL((gemm_bf16x3<false>), G(kB, kNE), 256, 0, stream,
                     w + o_ctx + (size_t)kNE * kD, w + o_ctx, (const float*)nullptr,
                     (float*)d_out, kB, kNE, kD);
}

// Round 6
// 458.529 us; speedup vs baseline: 2.2734x; 1.2565x over previous
//
#include <hip/hip_runtime.h>
#include <hip/hip_bf16.h>
#include <math.h>

namespace {
constexpr int kNE   = 2048;
constexpr int kB    = 512;
constexpr int kDin  = 768;
constexpr int kD    = 512;
constexpr int kP    = 49;
constexpr int kNtot = kNE + kB;   // 2560
}

typedef __attribute__((ext_vector_type(8))) short bf16x8;
typedef __attribute__((ext_vector_type(4))) float f32x4;

__device__ inline ushort f2bf(float f) {  // RNE fp32 -> bf16 bits
  unsigned u = __float_as_uint(f);
  return (ushort)((u + 0x7fffu + ((u >> 16) & 1u)) >> 16);
}

// split v = hi + lo: hi = truncate-to-bf16 (exact), lo = rne(v - hi).
__device__ inline void split4(const float4 v, ushort4& h, ushort4& l) {
  unsigned ux = __float_as_uint(v.x), uy = __float_as_uint(v.y),
           uz = __float_as_uint(v.z), uw = __float_as_uint(v.w);
  h.x = (ushort)(ux >> 16); h.y = (ushort)(uy >> 16);
  h.z = (ushort)(uz >> 16); h.w = (ushort)(uw >> 16);
  l.x = f2bf(v.x - __uint_as_float(ux & 0xFFFF0000u));
  l.y = f2bf(v.y - __uint_as_float(uy & 0xFFFF0000u));
  l.z = f2bf(v.z - __uint_as_float(uz & 0xFFFF0000u));
  l.w = f2bf(v.w - __uint_as_float(uw & 0xFFFF0000u));
}

// ---------------------------------------------------------------------------
// Job-batched compensated bf16x3 MFMA GEMM.
// C[M,N] = act(A[M,K] @ Bt[N,K]^T + bias); D = Ah*Bh + Al*Bh + Ah*Bl.
// 64x128 tile (small-shape friendly: 2x the blocks of 128^2), 256 thr,
// 4 waves each owning 64 rows x 32 cols (acc 4x2). BK=32.
// Requires M%64==0, N%128==0, K%32==0 (true at all call sites).
// Up to 4 independent GEMMs share one dispatch (fills the 256-CU grid).
// ---------------------------------------------------------------------------
struct GemmJob {
  const float* A; const float* Bt; const float* bias; float* C;
  int M, N, K, relu;
};
struct GemmBatch {
  GemmJob j[4];
  int prefix[5];   // block-range per job; prefix[njobs] = total blocks
};

__global__ __launch_bounds__(256) void gemm_batch(GemmBatch batch) {
  int ji = 0;
  { const int bid = blockIdx.x;
    while (bid >= batch.prefix[ji + 1]) ++ji; }
  const GemmJob jb = batch.j[ji];
  const int local = blockIdx.x - batch.prefix[ji];
  const int nbx = jb.N >> 7;
  const int by = local / nbx;
  const int bx = local - by * nbx;
  const int row0 = by * 64;
  const int col0 = bx * 128;
  const int K = jb.K;

  __shared__ ushort Ah[64][40];    // +8 pad -> 80B row stride
  __shared__ ushort Al[64][40];
  __shared__ ushort Bh[128][40];
  __shared__ ushort Bl[128][40];

  const int tid  = threadIdx.x;
  const int lane = tid & 63;
  const int w    = tid >> 6;       // wave id -> col slab [w*32, w*32+32)
  const int fr   = lane & 15;
  const int fk   = (lane >> 4) * 8;

  f32x4 acc[4][2] = {};

  for (int k0 = 0; k0 < K; k0 += 32) {
    // stage A (64x32): 2 float4/thread
#pragma unroll
    for (int i = 0; i < 2; ++i) {
      const int s  = tid + i * 256;   // 0..511
      const int r  = s >> 3;          // 0..63
      const int f4 = s & 7;
      float4 va = *(const float4*)&jb.A[(size_t)(row0 + r) * K + k0 + f4 * 4];
      ushort4 h, l; split4(va, h, l);
      *(ushort4*)&Ah[r][f4 * 4] = h;
      *(ushort4*)&Al[r][f4 * 4] = l;
    }
    // stage Bt (128x32): 4 float4/thread
#pragma unroll
    for (int i = 0; i < 4; ++i) {
      const int s  = tid + i * 256;   // 0..1023
      const int r  = s >> 3;          // 0..127
      const int f4 = s & 7;
      float4 vb = *(const float4*)&jb.Bt[(size_t)(col0 + r) * K + k0 + f4 * 4];
      ushort4 h, l; split4(vb, h, l);
      *(ushort4*)&Bh[r][f4 * 4] = h;
      *(ushort4*)&Bl[r][f4 * 4] = l;
    }
    __syncthreads();

    bf16x8 bh[2], bl[2];
#pragma unroll
    for (int n = 0; n < 2; ++n) {
      bh[n] = *(const bf16x8*)&Bh[w * 32 + n * 16 + fr][fk];
      bl[n] = *(const bf16x8*)&Bl[w * 32 + n * 16 + fr][fk];
    }
#pragma unroll
    for (int m = 0; m < 4; ++m) {
      bf16x8 ah = *(const bf16x8*)&Ah[m * 16 + fr][fk];
      bf16x8 al = *(const bf16x8*)&Al[m * 16 + fr][fk];
#pragma unroll
      for (int n = 0; n < 2; ++n) {
        acc[m][n] = __builtin_amdgcn_mfma_f32_16x16x32_bf16(ah, bh[n], acc[m][n], 0, 0, 0);
        acc[m][n] = __builtin_amdgcn_mfma_f32_16x16x32_bf16(al, bh[n], acc[m][n], 0, 0, 0);
        acc[m][n] = __builtin_amdgcn_mfma_f32_16x16x32_bf16(ah, bl[n], acc[m][n], 0, 0, 0);
      }
    }
    __syncthreads();
  }

  // epilogue: C/D layout col = lane&15, row = (lane>>4)*4 + j  [m89-verified]
  const int fq = lane >> 4;
#pragma unroll
  for (int n = 0; n < 2; ++n) {
    const int col = col0 + w * 32 + n * 16 + fr;
    const float bv = jb.bias ? jb.bias[col] : 0.f;
#pragma unroll
    for (int m = 0; m < 4; ++m) {
      const int rbase = row0 + m * 16 + fq * 4;
#pragma unroll
      for (int jj = 0; jj < 4; ++jj) {
        float v = acc[m][n][jj] + bv;
        if (jb.relu) v = fmaxf(v, 0.f);
        jb.C[(size_t)(rbase + jj) * jb.N + col] = v;
      }
    }
  }
}

// ---------------------------------------------------------------------------
// Single-pass online-softmax attention pooling. Block per n, 256 threads;
// thread t owns dims {t, t+256, t+512}. Tokens read exactly once (385 MB).
// ---------------------------------------------------------------------------
__global__ __launch_bounds__(256) void attn_pool(
    const float* __restrict__ ent_toks, const float* __restrict__ men_toks,
    const float* __restrict__ u, float* __restrict__ ws768) {
  const int n = blockIdx.x;
  const float* toks = (n < kNE) ? ent_toks + (size_t)n * kP * kDin
                                : men_toks + (size_t)(n - kNE) * kP * kDin;
  const float* un = u + (size_t)n * kDin;
  const int t = threadIdx.x;
  const int lane = t & 63, wave = t >> 6;

  const float u0 = un[t], u1 = un[t + 256], u2 = un[t + 512];

  __shared__ float rs[2][4];
  float m = -INFINITY, l = 0.f, a0 = 0.f, a1 = 0.f, a2 = 0.f;
  const float scale = 0.044194173824159216f;  // 512^-0.5

  for (int p = 0; p < kP; ++p) {
    const float* tp = toks + (size_t)p * kDin;
    const float t0 = tp[t], t1 = tp[t + 256], t2 = tp[t + 512];
    float d = fmaf(t0, u0, fmaf(t1, u1, t2 * u2));
    for (int o = 32; o; o >>= 1) d += __shfl_xor(d, o);
    if (lane == 0) rs[p & 1][wave] = d;
    __syncthreads();
    const float s = (rs[p & 1][0] + rs[p & 1][1] + rs[p & 1][2] + rs[p & 1][3]) * scale;
    const float mn = fmaxf(m, s);
    const float c = __expf(m - mn);   // 0 on first iter
    const float e = __expf(s - mn);
    l = l * c + e;
    a0 = fmaf(a0, c, e * t0); a1 = fmaf(a1, c, e * t1); a2 = fmaf(a2, c, e * t2);
    m = mn;
  }
  const float inv = 1.f / l;
  float* wr = ws768 + (size_t)n * kDin;
  wr[t] = a0 * inv; wr[t + 256] = a1 * inv; wr[t + 512] = a2 * inv;
}

// ---------------------------------------------------------------------------
struct TransJob { const float* src; float* dst; int R, C; };
struct TransArgs { TransJob j[7]; };

__global__ __launch_bounds__(256) void transpose7(TransArgs a) {
  const TransJob jb = a.j[blockIdx.z];
  const int r0 = blockIdx.y * 32, c0 = blockIdx.x * 32;
  if (r0 >= jb.R || c0 >= jb.C) return;
  __shared__ float tl[32][33];
  const int tx = threadIdx.x & 31, ty = threadIdx.x >> 5;  // 32x8
#pragma unroll
  for (int i = 0; i < 32; i += 8)
    tl[ty + i][tx] = jb.src[(size_t)(r0 + ty + i) * jb.C + c0 + tx];
  __syncthreads();
#pragma unroll
  for (int i = 0; i < 32; i += 8)
    jb.dst[(size_t)(c0 + ty + i) * jb.R + r0 + tx] = tl[tx][ty + i];
}

// ---------------------------------------------------------------------------
// Parallel GEMV: out[j] = sum_k vec[k]*W[k*N+j] + badd[j]. Block per column.
// ---------------------------------------------------------------------------
__global__ __launch_bounds__(256) void gemv_bias(const float* __restrict__ vec,
                                                 const float* __restrict__ W,
                                                 const float* __restrict__ badd,
                                                 float* __restrict__ out, int K, int N) {
  const int j = blockIdx.x;
  const int t = threadIdx.x;
  float acc = 0.f;
  for (int k = t; k < K; k += 256) acc = fmaf(vec[k], W[(size_t)k * N + j], acc);
  for (int o = 32; o; o >>= 1) acc += __shfl_xor(acc, o);
  __shared__ float r[4];
  if ((t & 63) == 0) r[t >> 6] = acc;
  __syncthreads();
  if (t == 0) out[j] = r[0] + r[1] + r[2] + r[3] + badd[j];
}

// ---------------------------------------------------------------------------
__global__ __launch_bounds__(64) void moe_gate(
    const float* __restrict__ txt, const float* __restrict__ img,
    const float* __restrict__ gw, const float* __restrict__ gb,
    float* __restrict__ gate2) {
  const int n = blockIdx.x;
  const int lane = threadIdx.x;
  float a0 = 0.f, a1 = 0.f;
  for (int k = lane; k < kD; k += 64) {
    const float t = txt[(size_t)n * kD + k];
    a0 = fmaf(t, gw[k * 2 + 0], a0);
    a1 = fmaf(t, gw[k * 2 + 1], a1);
    const float im = img[(size_t)n * kD + k];
    a0 = fmaf(im, gw[(kD + k) * 2 + 0], a0);
    a1 = fmaf(im, gw[(kD + k) * 2 + 1], a1);
  }
  for (int o = 32; o; o >>= 1) { a0 += __shfl_xor(a0, o); a1 += __shfl_xor(a1, o); }
  if (lane == 0) {
    const float l0 = a0 + gb[0], l1 = a1 + gb[1];
    const float m = fmaxf(l0, l1);
    const float e0 = __expf(l0 - m), e1 = __expf(l1 - m);
    const float inv = 1.f / (e0 + e1);
    gate2[n * 2 + 0] = e0 * inv;
    gate2[n * 2 + 1] = e1 * inv;
  }
}

__global__ __launch_bounds__(256) void finalize_ln(
    const float* __restrict__ cls_p, const float* __restrict__ et,
    const float* __restrict__ ei, const float* __restrict__ gate2,
    const float* __restrict__ gfw, const float* __restrict__ gfb,
    const float* __restrict__ lng, const float* __restrict__ lnb,
    float* __restrict__ outp) {
  const int n = blockIdx.x;
  const int t = threadIdx.x;
  const int lane = t & 63, wave = t >> 6;
  const float* cp = cls_p + (size_t)n * kD;
  const float c0 = cp[t], c1 = cp[t + 256];

  float d = fmaf(c0, gfw[t], c1 * gfw[t + 256]);
  for (int o = 32; o; o >>= 1) d += __shfl_xor(d, o);
  __shared__ float rsh[4];
  __shared__ float gtb;
  if (lane == 0) rsh[wave] = d;
  __syncthreads();
  if (t == 0) gtb = tanhf(rsh[0] + rsh[1] + rsh[2] + rsh[3] + gfb[0]);
  __syncthreads();
  const float gt = gtb;
  const float g0 = gate2[n * 2 + 0], g1 = gate2[n * 2 + 1];

  const size_t base = (size_t)n * kD;
  const float y0 = c0 * gt + g0 * et[base + t]       + g1 * ei[base + t];
  const float y1 = c1 * gt + g0 * et[base + 256 + t] + g1 * ei[base + 256 + t];

  float s = y0 + y1, ss = fmaf(y0, y0, y1 * y1);
  for (int o = 32; o; o >>= 1) { s += __shfl_xor(s, o); ss += __shfl_xor(ss, o); }
  __shared__ float rsum[4], rssq[4];
  __shared__ float mb, ivb;
  if (lane == 0) { rsum[wave] = s; rssq[wave] = ss; }
  __syncthreads();
  if (t == 0) {
    const float S  = rsum[0] + rsum[1] + rsum[2] + rsum[3];
    const float SS = rssq[0] + rssq[1] + rssq[2] + rssq[3];
    const float mm = S / (float)kD;
    const float v  = SS / (float)kD - mm * mm;
    mb = mm; ivb = rsqrtf(v + 1e-5f);
  }
  __syncthreads();
  const float mm = mb, iv = ivb;
  outp[base + t]       = (y0 - mm) * iv * lng[t] + lnb[t];
  outp[base + 256 + t] = (y1 - mm) * iv * lng[t + 256] + lnb[t + 256];
}

// ---------------------------------------------------------------------------
extern "C" void kernel_launch(void* const* d_in, const int* in_sizes, int n_in,
                              void* d_out, int out_size, void* d_ws, size_t ws_size,
                              hipStream_t stream) {
  const float* ent_cls  = (const float*)d_in[0];
  const float* ent_tok  = (const float*)d_in[1];
  const float* men_cls  = (const float*)d_in[2];
  const float* men_tok  = (const float*)d_in[3];
  const float* text_w   = (const float*)d_in[4];
  const float* text_b   = (const float*)d_in[5];
  const float* img_w    = (const float*)d_in[6];
  const float* img_b    = (const float*)d_in[7];
  const float* gate_w   = (const float*)d_in[8];
  const float* gate_b   = (const float*)d_in[9];
  const float* ln_g     = (const float*)d_in[10];
  const float* ln_b     = (const float*)d_in[11];
  const float* match_w  = (const float*)d_in[12];
  const float* match_b  = (const float*)d_in[13];
  // d_in[14..18] (mh_query, mh_wq, mh_bq, mh_wk, mh_bk) provably unused
  const float* mh_wv    = (const float*)d_in[19];
  const float* mh_bv    = (const float*)d_in[20];
  const float* mh_wo    = (const float*)d_in[21];
  const float* mh_bo    = (const float*)d_in[22];
  const float* moe_gw   = (const float*)d_in[23];
  const float* moe_gb   = (const float*)d_in[24];
  const float* moe_tw1  = (const float*)d_in[25];
  const float* moe_tb1  = (const float*)d_in[26];
  const float* moe_tw2  = (const float*)d_in[27];
  const float* moe_tb2  = (const float*)d_in[28];
  const float* moe_iw1  = (const float*)d_in[29];
  const float* moe_ib1  = (const float*)d_in[30];
  const float* moe_iw2  = (const float*)d_in[31];
  const float* moe_ib2  = (const float*)d_in[32];

  float* w = (float*)d_ws;
  size_t o = 0;
  auto alloc = [&](size_t nf) { size_t r = o; o += (nf + 127) & ~(size_t)127; return r; };
  const size_t o_clsp   = alloc((size_t)kNtot * kD);
  const size_t o_u_ht   = alloc((size_t)kNtot * kDin);  // u, reused as h_t
  const size_t o_ws_hi  = alloc((size_t)kNtot * kDin);  // ws768, reused as h_i
  const size_t o_txt    = alloc((size_t)kNtot * kD);
  const size_t o_img    = alloc((size_t)kNtot * kD);
  const size_t o_et     = alloc((size_t)kNtot * kD);
  const size_t o_ei     = alloc((size_t)kNtot * kD);
  const size_t o_ctx    = alloc((size_t)kNtot * kD);
  const size_t o_WcombT = alloc((size_t)kD * kDin);     // [512,768]
  const size_t o_U      = alloc((size_t)kD * kD);
  const size_t o_WimgT  = alloc((size_t)kD * kD);
  const size_t o_bcomb  = alloc(kD);
  const size_t o_bt1    = alloc(kD);
  const size_t o_bimg   = alloc(kD);
  const size_t o_gate   = alloc((size_t)kNtot * 2);
  const size_t o_textWT = alloc((size_t)kD * kDin);     // [512,768]
  const size_t o_matchWT= alloc((size_t)kD * kD);
  const size_t o_mhWoT  = alloc((size_t)kD * kD);
  const size_t o_tw1T   = alloc((size_t)kD * kD);
  const size_t o_tw2T   = alloc((size_t)kD * kD);
  const size_t o_iw1T   = alloc((size_t)kD * kD);
  const size_t o_iw2T   = alloc((size_t)kD * kD);
  (void)ws_size; (void)n_in; (void)in_sizes; (void)out_size;

  auto nblk = [](int M, int N) { return (M / 64) * (N / 128); };
  auto launch_batch = [&](int njobs, GemmJob j0, GemmJob j1 = {}, GemmJob j2 = {},
                          GemmJob j3 = {}) {
    GemmBatch b{};
    b.j[0] = j0; b.j[1] = j1; b.j[2] = j2; b.j[3] = j3;
    b.prefix[0] = 0;
    for (int i = 0; i < 4; ++i)
      b.prefix[i + 1] = b.prefix[i] + (i < njobs ? nblk(b.j[i].M, b.j[i].N) : 0);
    hipLaunchKernelGGL(gemm_batch, dim3(b.prefix[njobs]), 256, 0, stream, b);
  };

  // bias folds (independent of everything else)
  hipLaunchKernelGGL(gemv_bias, dim3(kD), 256, 0, stream,
                     img_b, match_w, match_b, w + o_bcomb, kD, kD);
  hipLaunchKernelGGL(gemv_bias, dim3(kD), 256, 0, stream,
                     match_b, mh_wv, mh_bv, w + o_bt1, kD, kD);

  // 0. transpose all [K,N] weights -> [N,K]
  TransArgs ta;
  ta.j[0] = { text_w,  w + o_textWT,  kDin, kD };
  ta.j[1] = { match_w, w + o_matchWT, kD,   kD };
  ta.j[2] = { mh_wo,   w + o_mhWoT,   kD,   kD };
  ta.j[3] = { moe_tw1, w + o_tw1T,    kD,   kD };
  ta.j[4] = { moe_tw2, w + o_tw2T,    kD,   kD };
  ta.j[5] = { moe_iw1, w + o_iw1T,    kD,   kD };
  ta.j[6] = { moe_iw2, w + o_iw2T,    kD,   kD };
  hipLaunchKernelGGL(transpose7, dim3(16, 24, 7), 256, 0, stream, ta);

  // D1: cls_p(ent), cls_p(men), WcombT, U   [240 blocks]
  launch_batch(4,
    GemmJob{ ent_cls,      w + o_textWT,  text_b, w + o_clsp,                     kNE, kD,   kDin, 0 },
    GemmJob{ men_cls,      w + o_textWT,  text_b, w + o_clsp + (size_t)kNE * kD,  kB,  kD,   kDin, 0 },
    GemmJob{ w + o_matchWT, img_w,        nullptr, w + o_WcombT,                  kD,  kDin, kD,   0 },
    GemmJob{ w + o_mhWoT,  mh_wv,         nullptr, w + o_U,                       kD,  kD,   kD,   0 });

  hipLaunchKernelGGL(gemv_bias, dim3(kD), 256, 0, stream,
                     w + o_bt1, mh_wo, mh_bo, w + o_bimg, kD, kD);

  // D2: u = cls_p@img_w^T, WimgT = U@match_w^T   [272 blocks]
  launch_batch(2,
    GemmJob{ w + o_clsp, img_w,   nullptr, w + o_u_ht,  kNtot, kDin, kD, 0 },
    GemmJob{ w + o_U,    match_w, nullptr, w + o_WimgT, kD,    kD,   kD, 0 });

  // D3: single-pass softmax pooling
  hipLaunchKernelGGL(attn_pool, dim3(kNtot), 256, 0, stream,
                     ent_tok, men_tok, w + o_u_ht, w + o_ws_hi);

  // D4: txt = ws768@Wcomb + bcomb ; img = cls_p@Wimg + bimg   [320 blocks]
  launch_batch(2,
    GemmJob{ w + o_ws_hi, w + o_WcombT, w + o_bcomb, w + o_txt, kNtot, kD, kDin, 0 },
    GemmJob{ w + o_clsp,  w + o_WimgT,  w + o_bimg,  w + o_img, kNtot, kD, kD,   0 });

  // D5: MoE gate
  hipLaunchKernelGGL(moe_gate, dim3(kNtot), 64, 0, stream,
                     w + o_txt, w + o_img, moe_gw, moe_gb, w + o_gate);

  // D6: expert hidden layers (relu)   [320 blocks]
  launch_batch(2,
    GemmJob{ w + o_txt, w + o_tw1T, moe_tb1, w + o_u_ht,  kNtot, kD, kD, 1 },
    GemmJob{ w + o_img, w + o_iw1T, moe_ib1, w + o_ws_hi, kNtot, kD, kD, 1 });

  // D7: expert output layers   [320 blocks]
  launch_batch(2,
    GemmJob{ w + o_u_ht,  w + o_tw2T, moe_tb2, w + o_et, kNtot, kD, kD, 0 },
    GemmJob{ w + o_ws_hi, w + o_iw2T, moe_ib2, w + o_ei, kNtot, kD, kD, 0 });

  // D8: finalize (tanh-gate + MoE combine + LN) -> ctx
  hipLaunchKernelGGL(finalize_ln, dim3(kNtot), 256, 0, stream,
                     w + o_clsp, w + o_et, w + o_ei, w + o_gate,
                     gate_w, gate_b, ln_g, ln_b, w + o_ctx);

  // D9: out = m_ctx @ e_ctx^T   [128 blocks]
  launch_batch(1,
    GemmJob{ w + o_ctx + (size_t)kNE * kD, w + o_ctx, nullptr, (float*)d_out,
             kB, kNE, kD, 0 });
}

// Round 7
// 288.060 us; speedup vs baseline: 3.6187x; 1.5918x over previous
//
#include <hip/hip_runtime.h>
#include <hip/hip_bf16.h>
#include <math.h>

namespace {
constexpr int kNE   = 2048;
constexpr int kB    = 512;
constexpr int kDin  = 768;
constexpr int kD    = 512;
constexpr int kP    = 49;
constexpr int kNtot = kNE + kB;   // 2560
}

typedef __attribute__((ext_vector_type(8))) short bf16x8;
typedef __attribute__((ext_vector_type(4))) float f32x4;

__device__ inline ushort f2bf(float f) {  // RNE fp32 -> bf16 bits
  unsigned u = __float_as_uint(f);
  return (ushort)((u + 0x7fffu + ((u >> 16) & 1u)) >> 16);
}
// v = hi + lo (hi = truncate-to-bf16, exact; lo = rne(v - hi), ~2^-17 rel)
__device__ inline void split1(float v, ushort& h, ushort& l) {
  unsigned u = __float_as_uint(v);
  h = (ushort)(u >> 16);
  l = f2bf(v - __uint_as_float(u & 0xFFFF0000u));
}

// ---------------------------------------------------------------------------
// Job-batched compensated bf16x3 MFMA GEMM on PRE-SPLIT operands.
// C = act(A @ Bt^T + bias); D = Ah*Bh + Al*Bh + Ah*Bl (fp32-grade).
// Operands are packed bf16 hi/lo ([M,K],[N,K] row-major). Inner loop is
// pure ushort8 load -> LDS -> MFMA (the R6 per-tile split4 was VALU-bound).
// 64x128 tile, 256 thr, 4 waves each 64r x 32c (acc 4x2), BK=32.
// Epilogue can emit fp32 and/or split hi/lo for chaining.
// ---------------------------------------------------------------------------
struct GemmJob {
  const ushort *Ah, *Al;    // [M,K] bf16 hi/lo
  const ushort *Bh, *Bl;    // [N,K] bf16 hi/lo
  const float* bias;
  float* Cf;                // optional fp32 out
  ushort *Ch, *Cl;          // optional split out
  int M, N, K, relu;
};
struct GemmBatch { GemmJob j[4]; int prefix[5]; };

__global__ __launch_bounds__(256) void gemm_batch(GemmBatch batch) {
  int ji = 0;
  { const int bid = blockIdx.x;
    while (bid >= batch.prefix[ji + 1]) ++ji; }
  const GemmJob jb = batch.j[ji];
  const int local = blockIdx.x - batch.prefix[ji];
  const int nbx = jb.N >> 7;
  const int by = local / nbx;
  const int bx = local - by * nbx;
  const int row0 = by * 64;
  const int col0 = bx * 128;
  const int K = jb.K;

  __shared__ ushort Ahs[64][40];   // +8 pad -> 80B row stride
  __shared__ ushort Als[64][40];
  __shared__ ushort Bhs[128][40];
  __shared__ ushort Bls[128][40];

  const int tid  = threadIdx.x;
  const int lane = tid & 63;
  const int w    = tid >> 6;        // wave -> col slab [w*32, w*32+32)
  const int fr   = lane & 15;
  const int fk   = (lane >> 4) * 8;

  f32x4 acc[4][2] = {};

  const int ar = tid >> 2;          // A: 64 rows x 4 chunks of 8
  const int ak = (tid & 3) * 8;

  for (int k0 = 0; k0 < K; k0 += 32) {
    {
      const size_t ga = (size_t)(row0 + ar) * K + k0 + ak;
      *(bf16x8*)&Ahs[ar][ak] = *(const bf16x8*)&jb.Ah[ga];
      *(bf16x8*)&Als[ar][ak] = *(const bf16x8*)&jb.Al[ga];
    }
#pragma unroll
    for (int i = 0; i < 2; ++i) {
      const int s = tid + i * 256;  // B: 128 rows x 4 chunks
      const int br = s >> 2, bk = (s & 3) * 8;
      const size_t gb = (size_t)(col0 + br) * K + k0 + bk;
      *(bf16x8*)&Bhs[br][bk] = *(const bf16x8*)&jb.Bh[gb];
      *(bf16x8*)&Bls[br][bk] = *(const bf16x8*)&jb.Bl[gb];
    }
    __syncthreads();

    bf16x8 bh[2], bl[2];
#pragma unroll
    for (int n = 0; n < 2; ++n) {
      bh[n] = *(const bf16x8*)&Bhs[w * 32 + n * 16 + fr][fk];
      bl[n] = *(const bf16x8*)&Bls[w * 32 + n * 16 + fr][fk];
    }
#pragma unroll
    for (int m = 0; m < 4; ++m) {
      bf16x8 ah = *(const bf16x8*)&Ahs[m * 16 + fr][fk];
      bf16x8 al = *(const bf16x8*)&Als[m * 16 + fr][fk];
#pragma unroll
      for (int n = 0; n < 2; ++n) {
        acc[m][n] = __builtin_amdgcn_mfma_f32_16x16x32_bf16(ah, bh[n], acc[m][n], 0, 0, 0);
        acc[m][n] = __builtin_amdgcn_mfma_f32_16x16x32_bf16(al, bh[n], acc[m][n], 0, 0, 0);
        acc[m][n] = __builtin_amdgcn_mfma_f32_16x16x32_bf16(ah, bl[n], acc[m][n], 0, 0, 0);
      }
    }
    __syncthreads();
  }

  // epilogue: C/D layout col = lane&15, row = (lane>>4)*4 + j  [m89-verified]
  const int fq = lane >> 4;
#pragma unroll
  for (int n = 0; n < 2; ++n) {
    const int col = col0 + w * 32 + n * 16 + fr;
    const float bv = jb.bias ? jb.bias[col] : 0.f;
#pragma unroll
    for (int m = 0; m < 4; ++m) {
      const int rbase = row0 + m * 16 + fq * 4;
#pragma unroll
      for (int jj = 0; jj < 4; ++jj) {
        float v = acc[m][n][jj] + bv;
        if (jb.relu) v = fmaxf(v, 0.f);
        const size_t idx = (size_t)(rbase + jj) * jb.N + col;
        if (jb.Cf) jb.Cf[idx] = v;
        if (jb.Ch) { ushort h, l; split1(v, h, l); jb.Ch[idx] = h; jb.Cl[idx] = l; }
      }
    }
  }
}

// ---------------------------------------------------------------------------
// Batched plain split: fp32 array -> bf16 hi/lo pair. n4 = elems/4.
// ---------------------------------------------------------------------------
struct SplitJob { const float* src; ushort* hi; ushort* lo; int n4; };
struct SplitArgs { SplitJob j[5]; };
__global__ __launch_bounds__(256) void split_plain(SplitArgs a) {
  const SplitJob jb = a.j[blockIdx.y];
  const int i = blockIdx.x * 256 + threadIdx.x;
  if (i >= jb.n4) return;
  float4 v = *(const float4*)&jb.src[(size_t)i * 4];
  ushort4 h, l;
  split1(v.x, h.x, l.x); split1(v.y, h.y, l.y);
  split1(v.z, h.z, l.z); split1(v.w, h.w, l.w);
  *(ushort4*)&jb.hi[(size_t)i * 4] = h;
  *(ushort4*)&jb.lo[(size_t)i * 4] = l;
}

// ---------------------------------------------------------------------------
// Batched transpose+split: src fp32 [R,C] -> hi/lo bf16 [C,R].
// ---------------------------------------------------------------------------
struct TSJob { const float* src; ushort* hi; ushort* lo; int R, C; };
struct TSArgs { TSJob j[7]; };
__global__ __launch_bounds__(256) void trans_split(TSArgs a) {
  const TSJob jb = a.j[blockIdx.z];
  const int r0 = blockIdx.y * 32, c0 = blockIdx.x * 32;
  if (r0 >= jb.R || c0 >= jb.C) return;
  __shared__ float tl[32][33];
  const int tx = threadIdx.x & 31, ty = threadIdx.x >> 5;  // 32x8
#pragma unroll
  for (int i = 0; i < 32; i += 8)
    tl[ty + i][tx] = jb.src[(size_t)(r0 + ty + i) * jb.C + c0 + tx];
  __syncthreads();
#pragma unroll
  for (int i = 0; i < 32; i += 8) {
    ushort h, l; split1(tl[tx][ty + i], h, l);
    const size_t idx = (size_t)(c0 + ty + i) * jb.R + r0 + tx;
    jb.hi[idx] = h; jb.lo[idx] = l;
  }
}

// ---------------------------------------------------------------------------
// Single-pass online-softmax attention pooling; emits split bf16 output
// (it feeds only the txt GEMM). Tokens read exactly once (385 MB).
// ---------------------------------------------------------------------------
__global__ __launch_bounds__(256) void attn_pool(
    const float* __restrict__ ent_toks, const float* __restrict__ men_toks,
    const float* __restrict__ u, ushort* __restrict__ wh, ushort* __restrict__ wl) {
  const int n = blockIdx.x;
  const float* toks = (n < kNE) ? ent_toks + (size_t)n * kP * kDin
                                : men_toks + (size_t)(n - kNE) * kP * kDin;
  const float* un = u + (size_t)n * kDin;
  const int t = threadIdx.x;
  const int lane = t & 63, wave = t >> 6;

  const float u0 = un[t], u1 = un[t + 256], u2 = un[t + 512];

  __shared__ float rs[2][4];
  float m = -INFINITY, l = 0.f, a0 = 0.f, a1 = 0.f, a2 = 0.f;
  const float scale = 0.044194173824159216f;  // 512^-0.5

  for (int p = 0; p < kP; ++p) {
    const float* tp = toks + (size_t)p * kDin;
    const float t0 = tp[t], t1 = tp[t + 256], t2 = tp[t + 512];
    float d = fmaf(t0, u0, fmaf(t1, u1, t2 * u2));
    for (int o = 32; o; o >>= 1) d += __shfl_xor(d, o);
    if (lane == 0) rs[p & 1][wave] = d;
    __syncthreads();
    const float s = (rs[p & 1][0] + rs[p & 1][1] + rs[p & 1][2] + rs[p & 1][3]) * scale;
    const float mn = fmaxf(m, s);
    const float c = __expf(m - mn);   // 0 on first iter
    const float e = __expf(s - mn);
    l = l * c + e;
    a0 = fmaf(a0, c, e * t0); a1 = fmaf(a1, c, e * t1); a2 = fmaf(a2, c, e * t2);
    m = mn;
  }
  const float inv = 1.f / l;
  const size_t base = (size_t)n * kDin;
  ushort h, lo2;
  split1(a0 * inv, h, lo2); wh[base + t] = h;       wl[base + t] = lo2;
  split1(a1 * inv, h, lo2); wh[base + 256 + t] = h; wl[base + 256 + t] = lo2;
  split1(a2 * inv, h, lo2); wh[base + 512 + t] = h; wl[base + 512 + t] = lo2;
}

// ---------------------------------------------------------------------------
// Parallel GEMV: out[j] = sum_k vec[k]*W[k*N+j] + badd[j]. Block per column.
// ---------------------------------------------------------------------------
__global__ __launch_bounds__(256) void gemv_bias(const float* __restrict__ vec,
                                                 const float* __restrict__ W,
                                                 const float* __restrict__ badd,
                                                 float* __restrict__ out, int K, int N) {
  const int j = blockIdx.x;
  const int t = threadIdx.x;
  float acc = 0.f;
  for (int k = t; k < K; k += 256) acc = fmaf(vec[k], W[(size_t)k * N + j], acc);
  for (int o = 32; o; o >>= 1) acc += __shfl_xor(acc, o);
  __shared__ float r[4];
  if ((t & 63) == 0) r[t >> 6] = acc;
  __syncthreads();
  if (t == 0) out[j] = r[0] + r[1] + r[2] + r[3] + badd[j];
}

// ---------------------------------------------------------------------------
__global__ __launch_bounds__(64) void moe_gate(
    const float* __restrict__ txt, const float* __restrict__ img,
    const float* __restrict__ gw, const float* __restrict__ gb,
    float* __restrict__ gate2) {
  const int n = blockIdx.x;
  const int lane = threadIdx.x;
  float a0 = 0.f, a1 = 0.f;
  for (int k = lane; k < kD; k += 64) {
    const float t = txt[(size_t)n * kD + k];
    a0 = fmaf(t, gw[k * 2 + 0], a0);
    a1 = fmaf(t, gw[k * 2 + 1], a1);
    const float im = img[(size_t)n * kD + k];
    a0 = fmaf(im, gw[(kD + k) * 2 + 0], a0);
    a1 = fmaf(im, gw[(kD + k) * 2 + 1], a1);
  }
  for (int o = 32; o; o >>= 1) { a0 += __shfl_xor(a0, o); a1 += __shfl_xor(a1, o); }
  if (lane == 0) {
    const float l0 = a0 + gb[0], l1 = a1 + gb[1];
    const float m = fmaxf(l0, l1);
    const float e0 = __expf(l0 - m), e1 = __expf(l1 - m);
    const float inv = 1.f / (e0 + e1);
    gate2[n * 2 + 0] = e0 * inv;
    gate2[n * 2 + 1] = e1 * inv;
  }
}

// ---------------------------------------------------------------------------
// Finalize -> ctx emitted as split bf16 (feeds only the final GEMM).
// ---------------------------------------------------------------------------
__global__ __launch_bounds__(256) void finalize_ln(
    const float* __restrict__ cls_p, const float* __restrict__ et,
    const float* __restrict__ ei, const float* __restrict__ gate2,
    const float* __restrict__ gfw, const float* __restrict__ gfb,
    const float* __restrict__ lng, const float* __restrict__ lnb,
    ushort* __restrict__ ch, ushort* __restrict__ cl) {
  const int n = blockIdx.x;
  const int t = threadIdx.x;
  const int lane = t & 63, wave = t >> 6;
  const float* cp = cls_p + (size_t)n * kD;
  const float c0 = cp[t], c1 = cp[t + 256];

  float d = fmaf(c0, gfw[t], c1 * gfw[t + 256]);
  for (int o = 32; o; o >>= 1) d += __shfl_xor(d, o);
  __shared__ float rsh[4];
  __shared__ float gtb;
  if (lane == 0) rsh[wave] = d;
  __syncthreads();
  if (t == 0) gtb = tanhf(rsh[0] + rsh[1] + rsh[2] + rsh[3] + gfb[0]);
  __syncthreads();
  const float gt = gtb;
  const float g0 = gate2[n * 2 + 0], g1 = gate2[n * 2 + 1];

  const size_t base = (size_t)n * kD;
  const float y0 = c0 * gt + g0 * et[base + t]       + g1 * ei[base + t];
  const float y1 = c1 * gt + g0 * et[base + 256 + t] + g1 * ei[base + 256 + t];

  float s = y0 + y1, ss = fmaf(y0, y0, y1 * y1);
  for (int o = 32; o; o >>= 1) { s += __shfl_xor(s, o); ss += __shfl_xor(ss, o); }
  __shared__ float rsum[4], rssq[4];
  __shared__ float mb, ivb;
  if (lane == 0) { rsum[wave] = s; rssq[wave] = ss; }
  __syncthreads();
  if (t == 0) {
    const float S  = rsum[0] + rsum[1] + rsum[2] + rsum[3];
    const float SS = rssq[0] + rssq[1] + rssq[2] + rssq[3];
    const float mm = S / (float)kD;
    const float v  = SS / (float)kD - mm * mm;
    mb = mm; ivb = rsqrtf(v + 1e-5f);
  }
  __syncthreads();
  const float mm = mb, iv = ivb;
  ushort h, l;
  split1((y0 - mm) * iv * lng[t] + lnb[t], h, l);
  ch[base + t] = h; cl[base + t] = l;
  split1((y1 - mm) * iv * lng[t + 256] + lnb[t + 256], h, l);
  ch[base + 256 + t] = h; cl[base + 256 + t] = l;
}

// ---------------------------------------------------------------------------
extern "C" void kernel_launch(void* const* d_in, const int* in_sizes, int n_in,
                              void* d_out, int out_size, void* d_ws, size_t ws_size,
                              hipStream_t stream) {
  const float* ent_cls  = (const float*)d_in[0];
  const float* ent_tok  = (const float*)d_in[1];
  const float* men_cls  = (const float*)d_in[2];
  const float* men_tok  = (const float*)d_in[3];
  const float* text_w   = (const float*)d_in[4];
  const float* text_b   = (const float*)d_in[5];
  const float* img_w    = (const float*)d_in[6];
  const float* img_b    = (const float*)d_in[7];
  const float* gate_w   = (const float*)d_in[8];
  const float* gate_b   = (const float*)d_in[9];
  const float* ln_g     = (const float*)d_in[10];
  const float* ln_b     = (const float*)d_in[11];
  const float* match_w  = (const float*)d_in[12];
  const float* match_b  = (const float*)d_in[13];
  // d_in[14..18] (mh_query, mh_wq, mh_bq, mh_wk, mh_bk) provably unused
  const float* mh_wv    = (const float*)d_in[19];
  const float* mh_bv    = (const float*)d_in[20];
  const float* mh_wo    = (const float*)d_in[21];
  const float* mh_bo    = (const float*)d_in[22];
  const float* moe_gw   = (const float*)d_in[23];
  const float* moe_gb   = (const float*)d_in[24];
  const float* moe_tw1  = (const float*)d_in[25];
  const float* moe_tb1  = (const float*)d_in[26];
  const float* moe_tw2  = (const float*)d_in[27];
  const float* moe_tb2  = (const float*)d_in[28];
  const float* moe_iw1  = (const float*)d_in[29];
  const float* moe_ib1  = (const float*)d_in[30];
  const float* moe_iw2  = (const float*)d_in[31];
  const float* moe_ib2  = (const float*)d_in[32];
  (void)ws_size; (void)n_in; (void)in_sizes; (void)out_size;

  char* base = (char*)d_ws;
  size_t off = 0;
  auto allocB = [&](size_t bytes) -> char* {
    char* p = base + off; off = (off + bytes + 255) & ~(size_t)255; return p;
  };
  auto allocF = [&](size_t n) { return (float*)allocB(n * 4); };
  auto allocU = [&](size_t n) { return (ushort*)allocB(n * 2); };

  // fp32 intermediates
  float* clsp_f = allocF((size_t)kNtot * kD);
  float* u_f    = allocF((size_t)kNtot * kDin);
  float* txt_f  = allocF((size_t)kNtot * kD);
  float* img_f  = allocF((size_t)kNtot * kD);
  float* et_f   = allocF((size_t)kNtot * kD);
  float* ei_f   = allocF((size_t)kNtot * kD);
  float* bcomb  = allocF(kD);
  float* bt1    = allocF(kD);
  float* bimg   = allocF(kD);
  float* gate2  = allocF((size_t)kNtot * 2);
  // split pairs
  auto pair = [&](size_t n, ushort*& h, ushort*& l) { h = allocU(n); l = allocU(n); };
  ushort *ent_h,*ent_l,*men_h,*men_l,*imgw_h,*imgw_l,*matw_h,*matw_l,*mhwv_h,*mhwv_l;
  pair((size_t)kNE * kDin, ent_h, ent_l);
  pair((size_t)kB * kDin, men_h, men_l);
  pair((size_t)kDin * kD, imgw_h, imgw_l);
  pair((size_t)kD * kD, matw_h, matw_l);
  pair((size_t)kD * kD, mhwv_h, mhwv_l);
  ushort *textWT_h,*textWT_l,*matchWT_h,*matchWT_l,*mhWoT_h,*mhWoT_l;
  ushort *tw1T_h,*tw1T_l,*tw2T_h,*tw2T_l,*iw1T_h,*iw1T_l,*iw2T_h,*iw2T_l;
  pair((size_t)kD * kDin, textWT_h, textWT_l);
  pair((size_t)kD * kD, matchWT_h, matchWT_l);
  pair((size_t)kD * kD, mhWoT_h, mhWoT_l);
  pair((size_t)kD * kD, tw1T_h, tw1T_l);
  pair((size_t)kD * kD, tw2T_h, tw2T_l);
  pair((size_t)kD * kD, iw1T_h, iw1T_l);
  pair((size_t)kD * kD, iw2T_h, iw2T_l);
  ushort *clsp_h,*clsp_l,*U_h,*U_l,*WcombT_h,*WcombT_l,*WimgT_h,*WimgT_l;
  pair((size_t)kNtot * kD, clsp_h, clsp_l);
  pair((size_t)kD * kD, U_h, U_l);
  pair((size_t)kD * kDin, WcombT_h, WcombT_l);
  pair((size_t)kD * kD, WimgT_h, WimgT_l);
  ushort *ws_h,*ws_l,*txt_h,*txt_l,*img_h,*img_l,*ht_h,*ht_l,*hi_h,*hi_l,*ctx_h,*ctx_l;
  pair((size_t)kNtot * kDin, ws_h, ws_l);
  pair((size_t)kNtot * kD, txt_h, txt_l);
  pair((size_t)kNtot * kD, img_h, img_l);
  pair((size_t)kNtot * kD, ht_h, ht_l);
  pair((size_t)kNtot * kD, hi_h, hi_l);
  pair((size_t)kNtot * kD, ctx_h, ctx_l);

  auto nblk = [](int M, int N) { return (M / 64) * (N / 128); };
  auto launch_batch = [&](int njobs, GemmJob j0, GemmJob j1 = {}, GemmJob j2 = {},
                          GemmJob j3 = {}) {
    GemmBatch b{};
    b.j[0] = j0; b.j[1] = j1; b.j[2] = j2; b.j[3] = j3;
    b.prefix[0] = 0;
    for (int i = 0; i < 4; ++i)
      b.prefix[i + 1] = b.prefix[i] + (i < njobs ? nblk(b.j[i].M, b.j[i].N) : 0);
    hipLaunchKernelGGL(gemm_batch, dim3(b.prefix[njobs]), 256, 0, stream, b);
  };

  // S1: split raw fp32 operands (inputs + non-transposed weights)
  SplitArgs sa;
  sa.j[0] = { ent_cls, ent_h, ent_l, kNE * kDin / 4 };
  sa.j[1] = { men_cls, men_h, men_l, kB * kDin / 4 };
  sa.j[2] = { img_w,   imgw_h, imgw_l, kDin * kD / 4 };
  sa.j[3] = { match_w, matw_h, matw_l, kD * kD / 4 };
  sa.j[4] = { mh_wv,   mhwv_h, mhwv_l, kD * kD / 4 };
  hipLaunchKernelGGL(split_plain, dim3((kNE * kDin / 4 + 255) / 256, 5), 256, 0, stream, sa);

  // S2: transpose+split [K,N] weights -> [N,K]
  TSArgs ta;
  ta.j[0] = { text_w,  textWT_h,  textWT_l,  kDin, kD };
  ta.j[1] = { match_w, matchWT_h, matchWT_l, kD,   kD };
  ta.j[2] = { mh_wo,   mhWoT_h,   mhWoT_l,   kD,   kD };
  ta.j[3] = { moe_tw1, tw1T_h,    tw1T_l,    kD,   kD };
  ta.j[4] = { moe_tw2, tw2T_h,    tw2T_l,    kD,   kD };
  ta.j[5] = { moe_iw1, iw1T_h,    iw1T_l,    kD,   kD };
  ta.j[6] = { moe_iw2, iw2T_h,    iw2T_l,    kD,   kD };
  hipLaunchKernelGGL(trans_split, dim3(16, 24, 7), 256, 0, stream, ta);

  // bias folds (fp32, tiny)
  hipLaunchKernelGGL(gemv_bias, dim3(kD), 256, 0, stream,
                     img_b, match_w, match_b, bcomb, kD, kD);
  hipLaunchKernelGGL(gemv_bias, dim3(kD), 256, 0, stream,
                     match_b, mh_wv, mh_bv, bt1, kD, kD);

  // D1: cls_p(ent), cls_p(men), WcombT = matchWT@img_w^T, U = mhWoT@mh_wv^T
  launch_batch(4,
    GemmJob{ ent_h, ent_l, textWT_h, textWT_l, text_b,
             clsp_f, clsp_h, clsp_l, kNE, kD, kDin, 0 },
    GemmJob{ men_h, men_l, textWT_h, textWT_l, text_b,
             clsp_f + (size_t)kNE * kD, clsp_h + (size_t)kNE * kD,
             clsp_l + (size_t)kNE * kD, kB, kD, kDin, 0 },
    GemmJob{ matchWT_h, matchWT_l, imgw_h, imgw_l, nullptr,
             nullptr, WcombT_h, WcombT_l, kD, kDin, kD, 0 },
    GemmJob{ mhWoT_h, mhWoT_l, mhwv_h, mhwv_l, nullptr,
             nullptr, U_h, U_l, kD, kD, kD, 0 });

  hipLaunchKernelGGL(gemv_bias, dim3(kD), 256, 0, stream,
                     bt1, mh_wo, mh_bo, bimg, kD, kD);

  // D2: u = cls_p@img_w^T (fp32 only), WimgT = U@match_w^T (split only)
  launch_batch(2,
    GemmJob{ clsp_h, clsp_l, imgw_h, imgw_l, nullptr,
             u_f, nullptr, nullptr, kNtot, kDin, kD, 0 },
    GemmJob{ U_h, U_l, matw_h, matw_l, nullptr,
             nullptr, WimgT_h, WimgT_l, kD, kD, kD, 0 });

  // D3: single-pass softmax pooling -> ws (split)
  hipLaunchKernelGGL(attn_pool, dim3(kNtot), 256, 0, stream,
                     ent_tok, men_tok, u_f, ws_h, ws_l);

  // D4: txt = ws@Wcomb + bcomb ; img = cls_p@Wimg + bimg  (fp32 + split)
  launch_batch(2,
    GemmJob{ ws_h, ws_l, WcombT_h, WcombT_l, bcomb,
             txt_f, txt_h, txt_l, kNtot, kD, kDin, 0 },
    GemmJob{ clsp_h, clsp_l, WimgT_h, WimgT_l, bimg,
             img_f, img_h, img_l, kNtot, kD, kD, 0 });

  // D5: MoE gate
  hipLaunchKernelGGL(moe_gate, dim3(kNtot), 64, 0, stream,
                     txt_f, img_f, moe_gw, moe_gb, gate2);

  // D6: expert hidden layers (relu, split only)
  launch_batch(2,
    GemmJob{ txt_h, txt_l, tw1T_h, tw1T_l, moe_tb1,
             nullptr, ht_h, ht_l, kNtot, kD, kD, 1 },
    GemmJob{ img_h, img_l, iw1T_h, iw1T_l, moe_ib1,
             nullptr, hi_h, hi_l, kNtot, kD, kD, 1 });

  // D7: expert output layers (fp32 only)
  launch_batch(2,
    GemmJob{ ht_h, ht_l, tw2T_h, tw2T_l, moe_tb2,
             et_f, nullptr, nullptr, kNtot, kD, kD, 0 },
    GemmJob{ hi_h, hi_l, iw2T_h, iw2T_l, moe_ib2,
             ei_f, nullptr, nullptr, kNtot, kD, kD, 0 });

  // D8: finalize -> ctx (split)
  hipLaunchKernelGGL(finalize_ln, dim3(kNtot), 256, 0, stream,
                     clsp_f, et_f, ei_f, gate2,
                     gate_w, gate_b, ln_g, ln_b, ctx_h, ctx_l);

  // D9: out = m_ctx @ e_ctx^T
  launch_batch(1,
    GemmJob{ ctx_h + (size_t)kNE * kD, ctx_l + (size_t)kNE * kD,
             ctx_h, ctx_l, nullptr,
             (float*)d_out, nullptr, nullptr, kB, kNE, kD, 0 });
}

// Round 8
// 259.177 us; speedup vs baseline: 4.0220x; 1.1114x over previous
//
#include <hip/hip_runtime.h>
#include <hip/hip_bf16.h>
#include <math.h>

namespace {
constexpr int kNE   = 2048;
constexpr int kB    = 512;
constexpr int kDin  = 768;
constexpr int kD    = 512;
constexpr int kP    = 49;
constexpr int kNtot = kNE + kB;   // 2560
}

typedef __attribute__((ext_vector_type(8))) short bf16x8;
typedef __attribute__((ext_vector_type(4))) float f32x4;

__device__ inline ushort f2bf(float f) {  // RNE fp32 -> bf16 bits
  unsigned u = __float_as_uint(f);
  return (ushort)((u + 0x7fffu + ((u >> 16) & 1u)) >> 16);
}
// v = hi + lo (hi = truncate-to-bf16, exact; lo = rne(v - hi), ~2^-17 rel)
__device__ inline void split1(float v, ushort& h, ushort& l) {
  unsigned u = __float_as_uint(v);
  h = (ushort)(u >> 16);
  l = f2bf(v - __uint_as_float(u & 0xFFFF0000u));
}

// ---------------------------------------------------------------------------
// Job-batched compensated bf16x3 MFMA GEMM on pre-split operands,
// REG-STAGED DOUBLE-BUFFERED: while computing K-tile t from LDS buf[cur],
// tile t+1 (already in regs) is written to buf[cur^1] and tile t+2's global
// loads are issued. ONE barrier per K-tile; VMEM latency hides under MFMA.
// (R7 loop was latency-bound: 1.25 blocks/CU, serial stage->barrier->compute.)
// 64x128 tile, 256 thr, 4 waves each 64r x 32c (acc 4x2), BK=32.
// ---------------------------------------------------------------------------
struct GemmJob {
  const ushort *Ah, *Al;    // [M,K] bf16 hi/lo
  const ushort *Bh, *Bl;    // [N,K] bf16 hi/lo
  const float* bias;
  float* Cf;                // optional fp32 out
  ushort *Ch, *Cl;          // optional split out
  int M, N, K, relu;
};
struct GemmBatch { GemmJob j[4]; int prefix[5]; };

__global__ __launch_bounds__(256) void gemm_batch(GemmBatch batch) {
  int ji = 0;
  { const int bid = blockIdx.x;
    while (ji < 3 && bid >= batch.prefix[ji + 1]) ++ji; }
  const GemmJob jb = batch.j[ji];
  const int local = blockIdx.x - batch.prefix[ji];
  const int nbx = jb.N >> 7;
  const int by = local / nbx;
  const int bx = local - by * nbx;
  const int row0 = by * 64, col0 = bx * 128;
  const int K = jb.K;
  const int nt = K >> 5;

  __shared__ ushort Ahs[2][64][40], Als[2][64][40];   // +8 pad -> 80B stride
  __shared__ ushort Bhs[2][128][40], Bls[2][128][40]; // total 61.4 KB

  const int tid  = threadIdx.x;
  const int lane = tid & 63;
  const int w    = tid >> 6;        // wave -> col slab [w*32, w*32+32)
  const int fr   = lane & 15;
  const int fk   = (lane >> 4) * 8;
  const int sr   = tid >> 2;        // staging row 0..63
  const int sk   = (tid & 3) * 8;   // staging k-chunk

  const ushort* pAh  = jb.Ah + (size_t)(row0 + sr) * K + sk;
  const ushort* pAl  = jb.Al + (size_t)(row0 + sr) * K + sk;
  const ushort* pBh0 = jb.Bh + (size_t)(col0 + sr) * K + sk;
  const ushort* pBl0 = jb.Bl + (size_t)(col0 + sr) * K + sk;
  const ushort* pBh1 = jb.Bh + (size_t)(col0 + 64 + sr) * K + sk;
  const ushort* pBl1 = jb.Bl + (size_t)(col0 + 64 + sr) * K + sk;

  bf16x8 rAh, rAl, rBh0, rBl0, rBh1, rBl1;   // in-flight tile (24 VGPR)
  auto LOAD = [&](int t) {
    const int o = t * 32;
    rAh  = *(const bf16x8*)(pAh + o);  rAl  = *(const bf16x8*)(pAl + o);
    rBh0 = *(const bf16x8*)(pBh0 + o); rBl0 = *(const bf16x8*)(pBl0 + o);
    rBh1 = *(const bf16x8*)(pBh1 + o); rBl1 = *(const bf16x8*)(pBl1 + o);
  };
  auto STORE = [&](int b) {
    *(bf16x8*)&Ahs[b][sr][sk] = rAh;       *(bf16x8*)&Als[b][sr][sk] = rAl;
    *(bf16x8*)&Bhs[b][sr][sk] = rBh0;      *(bf16x8*)&Bls[b][sr][sk] = rBl0;
    *(bf16x8*)&Bhs[b][64 + sr][sk] = rBh1; *(bf16x8*)&Bls[b][64 + sr][sk] = rBl1;
  };

  f32x4 acc[4][2] = {};

  LOAD(0); STORE(0);
  if (nt > 1) LOAD(1);
  __syncthreads();

  for (int t = 0; t < nt; ++t) {
    const int cur = t & 1;
    bf16x8 bh[2], bl[2];
#pragma unroll
    for (int n = 0; n < 2; ++n) {
      bh[n] = *(const bf16x8*)&Bhs[cur][w * 32 + n * 16 + fr][fk];
      bl[n] = *(const bf16x8*)&Bls[cur][w * 32 + n * 16 + fr][fk];
    }
#pragma unroll
    for (int m = 0; m < 4; ++m) {
      bf16x8 ah = *(const bf16x8*)&Ahs[cur][m * 16 + fr][fk];
      bf16x8 al = *(const bf16x8*)&Als[cur][m * 16 + fr][fk];
#pragma unroll
      for (int n = 0; n < 2; ++n) {
        acc[m][n] = __builtin_amdgcn_mfma_f32_16x16x32_bf16(ah, bh[n], acc[m][n], 0, 0, 0);
        acc[m][n] = __builtin_amdgcn_mfma_f32_16x16x32_bf16(al, bh[n], acc[m][n], 0, 0, 0);
        acc[m][n] = __builtin_amdgcn_mfma_f32_16x16x32_bf16(ah, bl[n], acc[m][n], 0, 0, 0);
      }
    }
    if (t + 1 < nt) {
      STORE(cur ^ 1);                // tile t+1 regs -> other buffer
      if (t + 2 < nt) LOAD(t + 2);   // prefetch tile t+2
    }
    __syncthreads();                 // single barrier per K-tile
  }

  // epilogue: C/D layout col = lane&15, row = (lane>>4)*4 + j  [m89-verified]
  const int fq = lane >> 4;
#pragma unroll
  for (int n = 0; n < 2; ++n) {
    const int col = col0 + w * 32 + n * 16 + fr;
    const float bv = jb.bias ? jb.bias[col] : 0.f;
#pragma unroll
    for (int m = 0; m < 4; ++m) {
      const int rbase = row0 + m * 16 + fq * 4;
#pragma unroll
      for (int jj = 0; jj < 4; ++jj) {
        float v = acc[m][n][jj] + bv;
        if (jb.relu) v = fmaxf(v, 0.f);
        const size_t idx = (size_t)(rbase + jj) * jb.N + col;
        if (jb.Cf) jb.Cf[idx] = v;
        if (jb.Ch) { ushort h, l; split1(v, h, l); jb.Ch[idx] = h; jb.Cl[idx] = l; }
      }
    }
  }
}

// ---------------------------------------------------------------------------
// Batched plain split: fp32 array -> bf16 hi/lo pair. n4 = elems/4.
// ---------------------------------------------------------------------------
struct SplitJob { const float* src; ushort* hi; ushort* lo; int n4; };
struct SplitArgs { SplitJob j[5]; };
__global__ __launch_bounds__(256) void split_plain(SplitArgs a) {
  const SplitJob jb = a.j[blockIdx.y];
  const int i = blockIdx.x * 256 + threadIdx.x;
  if (i >= jb.n4) return;
  float4 v = *(const float4*)&jb.src[(size_t)i * 4];
  ushort4 h, l;
  split1(v.x, h.x, l.x); split1(v.y, h.y, l.y);
  split1(v.z, h.z, l.z); split1(v.w, h.w, l.w);
  *(ushort4*)&jb.hi[(size_t)i * 4] = h;
  *(ushort4*)&jb.lo[(size_t)i * 4] = l;
}

// ---------------------------------------------------------------------------
// Batched transpose+split: src fp32 [R,C] -> hi/lo bf16 [C,R].
// ---------------------------------------------------------------------------
struct TSJob { const float* src; ushort* hi; ushort* lo; int R, C; };
struct TSArgs { TSJob j[7]; };
__global__ __launch_bounds__(256) void trans_split(TSArgs a) {
  const TSJob jb = a.j[blockIdx.z];
  const int r0 = blockIdx.y * 32, c0 = blockIdx.x * 32;
  if (r0 >= jb.R || c0 >= jb.C) return;
  __shared__ float tl[32][33];
  const int tx = threadIdx.x & 31, ty = threadIdx.x >> 5;  // 32x8
#pragma unroll
  for (int i = 0; i < 32; i += 8)
    tl[ty + i][tx] = jb.src[(size_t)(r0 + ty + i) * jb.C + c0 + tx];
  __syncthreads();
#pragma unroll
  for (int i = 0; i < 32; i += 8) {
    ushort h, l; split1(tl[tx][ty + i], h, l);
    const size_t idx = (size_t)(c0 + ty + i) * jb.R + r0 + tx;
    jb.hi[idx] = h; jb.lo[idx] = l;
  }
}

// ---------------------------------------------------------------------------
// Single-pass online-softmax attention pooling; emits split bf16 output.
// Tokens read exactly once (385 MB) -> HBM-bound floor ~62 us.
// ---------------------------------------------------------------------------
__global__ __launch_bounds__(256) void attn_pool(
    const float* __restrict__ ent_toks, const float* __restrict__ men_toks,
    const float* __restrict__ u, ushort* __restrict__ wh, ushort* __restrict__ wl) {
  const int n = blockIdx.x;
  const float* toks = (n < kNE) ? ent_toks + (size_t)n * kP * kDin
                                : men_toks + (size_t)(n - kNE) * kP * kDin;
  const float* un = u + (size_t)n * kDin;
  const int t = threadIdx.x;
  const int lane = t & 63, wave = t >> 6;

  const float u0 = un[t], u1 = un[t + 256], u2 = un[t + 512];

  __shared__ float rs[2][4];
  float m = -INFINITY, l = 0.f, a0 = 0.f, a1 = 0.f, a2 = 0.f;
  const float scale = 0.044194173824159216f;  // 512^-0.5

  for (int p = 0; p < kP; ++p) {
    const float* tp = toks + (size_t)p * kDin;
    const float t0 = tp[t], t1 = tp[t + 256], t2 = tp[t + 512];
    float d = fmaf(t0, u0, fmaf(t1, u1, t2 * u2));
    for (int o = 32; o; o >>= 1) d += __shfl_xor(d, o);
    if (lane == 0) rs[p & 1][wave] = d;
    __syncthreads();
    const float s = (rs[p & 1][0] + rs[p & 1][1] + rs[p & 1][2] + rs[p & 1][3]) * scale;
    const float mn = fmaxf(m, s);
    const float c = __expf(m - mn);   // 0 on first iter
    const float e = __expf(s - mn);
    l = l * c + e;
    a0 = fmaf(a0, c, e * t0); a1 = fmaf(a1, c, e * t1); a2 = fmaf(a2, c, e * t2);
    m = mn;
  }
  const float inv = 1.f / l;
  const size_t base = (size_t)n * kDin;
  ushort h, lo2;
  split1(a0 * inv, h, lo2); wh[base + t] = h;       wl[base + t] = lo2;
  split1(a1 * inv, h, lo2); wh[base + 256 + t] = h; wl[base + 256 + t] = lo2;
  split1(a2 * inv, h, lo2); wh[base + 512 + t] = h; wl[base + 512 + t] = lo2;
}

// ---------------------------------------------------------------------------
// Parallel GEMV: out[j] = sum_k vec[k]*W[k*N+j] + badd[j]. Block per column.
// ---------------------------------------------------------------------------
__global__ __launch_bounds__(256) void gemv_bias(const float* __restrict__ vec,
                                                 const float* __restrict__ W,
                                                 const float* __restrict__ badd,
                                                 float* __restrict__ out, int K, int N) {
  const int j = blockIdx.x;
  const int t = threadIdx.x;
  float acc = 0.f;
  for (int k = t; k < K; k += 256) acc = fmaf(vec[k], W[(size_t)k * N + j], acc);
  for (int o = 32; o; o >>= 1) acc += __shfl_xor(acc, o);
  __shared__ float r[4];
  if ((t & 63) == 0) r[t >> 6] = acc;
  __syncthreads();
  if (t == 0) out[j] = r[0] + r[1] + r[2] + r[3] + badd[j];
}

// ---------------------------------------------------------------------------
// Finalize with FUSED MoE gate (was a separate dispatch):
// gate = softmax([txt,img]@gw + gb); gt = tanh(cls_p.gfw + gfb);
// y = cls_p*gt + g0*et + g1*ei; ctx = LN(y) emitted as split bf16.
// ---------------------------------------------------------------------------
__global__ __launch_bounds__(256) void finalize_ln(
    const float* __restrict__ cls_p, const float* __restrict__ et,
    const float* __restrict__ ei, const float* __restrict__ txt,
    const float* __restrict__ img,
    const float* __restrict__ gw, const float* __restrict__ gb,
    const float* __restrict__ gfw, const float* __restrict__ gfb,
    const float* __restrict__ lng, const float* __restrict__ lnb,
    ushort* __restrict__ ch, ushort* __restrict__ cl) {
  const int n = blockIdx.x;
  const int t = threadIdx.x;
  const int lane = t & 63, wave = t >> 6;
  const size_t base = (size_t)n * kD;
  const float c0 = cls_p[base + t], c1 = cls_p[base + 256 + t];

  // three block reductions: tanh-gate dot, moe-gate dot0, dot1
  const float t0 = txt[base + t], t1 = txt[base + 256 + t];
  const float i0 = img[base + t], i1 = img[base + 256 + t];
  float d  = fmaf(c0, gfw[t], c1 * gfw[t + 256]);
  float p0 = fmaf(t0, gw[t * 2 + 0], fmaf(t1, gw[(t + 256) * 2 + 0],
             fmaf(i0, gw[(512 + t) * 2 + 0], i1 * gw[(768 + t) * 2 + 0])));
  float p1 = fmaf(t0, gw[t * 2 + 1], fmaf(t1, gw[(t + 256) * 2 + 1],
             fmaf(i0, gw[(512 + t) * 2 + 1], i1 * gw[(768 + t) * 2 + 1])));
  for (int o = 32; o; o >>= 1) {
    d += __shfl_xor(d, o); p0 += __shfl_xor(p0, o); p1 += __shfl_xor(p1, o);
  }
  __shared__ float rd[4], r0[4], r1[4];
  __shared__ float gtb, g0b, g1b;
  if (lane == 0) { rd[wave] = d; r0[wave] = p0; r1[wave] = p1; }
  __syncthreads();
  if (t == 0) {
    gtb = tanhf(rd[0] + rd[1] + rd[2] + rd[3] + gfb[0]);
    const float l0 = r0[0] + r0[1] + r0[2] + r0[3] + gb[0];
    const float l1 = r1[0] + r1[1] + r1[2] + r1[3] + gb[1];
    const float mm = fmaxf(l0, l1);
    const float e0 = __expf(l0 - mm), e1 = __expf(l1 - mm);
    const float inv = 1.f / (e0 + e1);
    g0b = e0 * inv; g1b = e1 * inv;
  }
  __syncthreads();
  const float gt = gtb, g0 = g0b, g1 = g1b;

  const float y0 = c0 * gt + g0 * et[base + t]       + g1 * ei[base + t];
  const float y1 = c1 * gt + g0 * et[base + 256 + t] + g1 * ei[base + 256 + t];

  float s = y0 + y1, ss = fmaf(y0, y0, y1 * y1);
  for (int o = 32; o; o >>= 1) { s += __shfl_xor(s, o); ss += __shfl_xor(ss, o); }
  __shared__ float rsum[4], rssq[4];
  __shared__ float mb, ivb;
  if (lane == 0) { rsum[wave] = s; rssq[wave] = ss; }
  __syncthreads();
  if (t == 0) {
    const float S  = rsum[0] + rsum[1] + rsum[2] + rsum[3];
    const float SS = rssq[0] + rssq[1] + rssq[2] + rssq[3];
    const float mm = S / (float)kD;
    const float v  = SS / (float)kD - mm * mm;
    mb = mm; ivb = rsqrtf(v + 1e-5f);
  }
  __syncthreads();
  const float mm = mb, iv = ivb;
  ushort h, l;
  split1((y0 - mm) * iv * lng[t] + lnb[t], h, l);
  ch[base + t] = h; cl[base + t] = l;
  split1((y1 - mm) * iv * lng[t + 256] + lnb[t + 256], h, l);
  ch[base + 256 + t] = h; cl[base + 256 + t] = l;
}

// ---------------------------------------------------------------------------
extern "C" void kernel_launch(void* const* d_in, const int* in_sizes, int n_in,
                              void* d_out, int out_size, void* d_ws, size_t ws_size,
                              hipStream_t stream) {
  const float* ent_cls  = (const float*)d_in[0];
  const float* ent_tok  = (const float*)d_in[1];
  const float* men_cls  = (const float*)d_in[2];
  const float* men_tok  = (const float*)d_in[3];
  const float* text_w   = (const float*)d_in[4];
  const float* text_b   = (const float*)d_in[5];
  const float* img_w    = (const float*)d_in[6];
  const float* img_b    = (const float*)d_in[7];
  const float* gate_w   = (const float*)d_in[8];
  const float* gate_b   = (const float*)d_in[9];
  const float* ln_g     = (const float*)d_in[10];
  const float* ln_b     = (const float*)d_in[11];
  const float* match_w  = (const float*)d_in[12];
  const float* match_b  = (const float*)d_in[13];
  // d_in[14..18] (mh_query, mh_wq, mh_bq, mh_wk, mh_bk) provably unused
  const float* mh_wv    = (const float*)d_in[19];
  const float* mh_bv    = (const float*)d_in[20];
  const float* mh_wo    = (const float*)d_in[21];
  const float* mh_bo    = (const float*)d_in[22];
  const float* moe_gw   = (const float*)d_in[23];
  const float* moe_gb   = (const float*)d_in[24];
  const float* moe_tw1  = (const float*)d_in[25];
  const float* moe_tb1  = (const float*)d_in[26];
  const float* moe_tw2  = (const float*)d_in[27];
  const float* moe_tb2  = (const float*)d_in[28];
  const float* moe_iw1  = (const float*)d_in[29];
  const float* moe_ib1  = (const float*)d_in[30];
  const float* moe_iw2  = (const float*)d_in[31];
  const float* moe_ib2  = (const float*)d_in[32];
  (void)ws_size; (void)n_in; (void)in_sizes; (void)out_size;

  char* base = (char*)d_ws;
  size_t off = 0;
  auto allocB = [&](size_t bytes) -> char* {
    char* p = base + off; off = (off + bytes + 255) & ~(size_t)255; return p;
  };
  auto allocF = [&](size_t n) { return (float*)allocB(n * 4); };
  auto allocU = [&](size_t n) { return (ushort*)allocB(n * 2); };

  // fp32 intermediates
  float* clsp_f = allocF((size_t)kNtot * kD);
  float* u_f    = allocF((size_t)kNtot * kDin);
  float* txt_f  = allocF((size_t)kNtot * kD);
  float* img_f  = allocF((size_t)kNtot * kD);
  float* et_f   = allocF((size_t)kNtot * kD);
  float* ei_f   = allocF((size_t)kNtot * kD);
  float* bcomb  = allocF(kD);
  float* bt1    = allocF(kD);
  float* bimg   = allocF(kD);
  // split pairs
  auto pair = [&](size_t n, ushort*& h, ushort*& l) { h = allocU(n); l = allocU(n); };
  ushort *ent_h,*ent_l,*men_h,*men_l,*imgw_h,*imgw_l,*matw_h,*matw_l,*mhwv_h,*mhwv_l;
  pair((size_t)kNE * kDin, ent_h, ent_l);
  pair((size_t)kB * kDin, men_h, men_l);
  pair((size_t)kDin * kD, imgw_h, imgw_l);
  pair((size_t)kD * kD, matw_h, matw_l);
  pair((size_t)kD * kD, mhwv_h, mhwv_l);
  ushort *textWT_h,*textWT_l,*matchWT_h,*matchWT_l,*mhWoT_h,*mhWoT_l;
  ushort *tw1T_h,*tw1T_l,*tw2T_h,*tw2T_l,*iw1T_h,*iw1T_l,*iw2T_h,*iw2T_l;
  pair((size_t)kD * kDin, textWT_h, textWT_l);
  pair((size_t)kD * kD, matchWT_h, matchWT_l);
  pair((size_t)kD * kD, mhWoT_h, mhWoT_l);
  pair((size_t)kD * kD, tw1T_h, tw1T_l);
  pair((size_t)kD * kD, tw2T_h, tw2T_l);
  pair((size_t)kD * kD, iw1T_h, iw1T_l);
  pair((size_t)kD * kD, iw2T_h, iw2T_l);
  ushort *clsp_h,*clsp_l,*U_h,*U_l,*WcombT_h,*WcombT_l,*WimgT_h,*WimgT_l;
  pair((size_t)kNtot * kD, clsp_h, clsp_l);
  pair((size_t)kD * kD, U_h, U_l);
  pair((size_t)kD * kDin, WcombT_h, WcombT_l);
  pair((size_t)kD * kD, WimgT_h, WimgT_l);
  ushort *ws_h,*ws_l,*txt_h,*txt_l,*img_h,*img_l,*ht_h,*ht_l,*hi_h,*hi_l,*ctx_h,*ctx_l;
  pair((size_t)kNtot * kDin, ws_h, ws_l);
  pair((size_t)kNtot * kD, txt_h, txt_l);
  pair((size_t)kNtot * kD, img_h, img_l);
  pair((size_t)kNtot * kD, ht_h, ht_l);
  pair((size_t)kNtot * kD, hi_h, hi_l);
  pair((size_t)kNtot * kD, ctx_h, ctx_l);

  auto nblk = [](int M, int N) { return (M / 64) * (N / 128); };
  auto launch_batch = [&](int njobs, GemmJob j0, GemmJob j1 = {}, GemmJob j2 = {},
                          GemmJob j3 = {}) {
    GemmBatch b{};
    b.j[0] = j0; b.j[1] = j1; b.j[2] = j2; b.j[3] = j3;
    b.prefix[0] = 0;
    for (int i = 0; i < 4; ++i)
      b.prefix[i + 1] = b.prefix[i] + (i < njobs ? nblk(b.j[i].M, b.j[i].N) : 0);
    hipLaunchKernelGGL(gemm_batch, dim3(b.prefix[njobs]), 256, 0, stream, b);
  };

  // S1: split raw fp32 operands (inputs + non-transposed weights)
  SplitArgs sa;
  sa.j[0] = { ent_cls, ent_h, ent_l, kNE * kDin / 4 };
  sa.j[1] = { men_cls, men_h, men_l, kB * kDin / 4 };
  sa.j[2] = { img_w,   imgw_h, imgw_l, kDin * kD / 4 };
  sa.j[3] = { match_w, matw_h, matw_l, kD * kD / 4 };
  sa.j[4] = { mh_wv,   mhwv_h, mhwv_l, kD * kD / 4 };
  hipLaunchKernelGGL(split_plain, dim3((kNE * kDin / 4 + 255) / 256, 5), 256, 0, stream, sa);

  // S2: transpose+split [K,N] weights -> [N,K]
  TSArgs ta;
  ta.j[0] = { text_w,  textWT_h,  textWT_l,  kDin, kD };
  ta.j[1] = { match_w, matchWT_h, matchWT_l, kD,   kD };
  ta.j[2] = { mh_wo,   mhWoT_h,   mhWoT_l,   kD,   kD };
  ta.j[3] = { moe_tw1, tw1T_h,    tw1T_l,    kD,   kD };
  ta.j[4] = { moe_tw2, tw2T_h,    tw2T_l,    kD,   kD };
  ta.j[5] = { moe_iw1, iw1T_h,    iw1T_l,    kD,   kD };
  ta.j[6] = { moe_iw2, iw2T_h,    iw2T_l,    kD,   kD };
  hipLaunchKernelGGL(trans_split, dim3(16, 24, 7), 256, 0, stream, ta);

  // bias folds (fp32, tiny)
  hipLaunchKernelGGL(gemv_bias, dim3(kD), 256, 0, stream,
                     img_b, match_w, match_b, bcomb, kD, kD);
  hipLaunchKernelGGL(gemv_bias, dim3(kD), 256, 0, stream,
                     match_b, mh_wv, mh_bv, bt1, kD, kD);

  // D1: cls_p(ent), cls_p(men), WcombT = matchWT@img_w^T, U = mhWoT@mh_wv^T
  launch_batch(4,
    GemmJob{ ent_h, ent_l, textWT_h, textWT_l, text_b,
             clsp_f, clsp_h, clsp_l, kNE, kD, kDin, 0 },
    GemmJob{ men_h, men_l, textWT_h, textWT_l, text_b,
             clsp_f + (size_t)kNE * kD, clsp_h + (size_t)kNE * kD,
             clsp_l + (size_t)kNE * kD, kB, kD, kDin, 0 },
    GemmJob{ matchWT_h, matchWT_l, imgw_h, imgw_l, nullptr,
             nullptr, WcombT_h, WcombT_l, kD, kDin, kD, 0 },
    GemmJob{ mhWoT_h, mhWoT_l, mhwv_h, mhwv_l, nullptr,
             nullptr, U_h, U_l, kD, kD, kD, 0 });

  hipLaunchKernelGGL(gemv_bias, dim3(kD), 256, 0, stream,
                     bt1, mh_wo, mh_bo, bimg, kD, kD);

  // D2: u = cls_p@img_w^T (fp32 only), WimgT = U@match_w^T (split only)
  launch_batch(2,
    GemmJob{ clsp_h, clsp_l, imgw_h, imgw_l, nullptr,
             u_f, nullptr, nullptr, kNtot, kDin, kD, 0 },
    GemmJob{ U_h, U_l, matw_h, matw_l, nullptr,
             nullptr, WimgT_h, WimgT_l, kD, kD, kD, 0 });

  // D3: single-pass softmax pooling -> ws (split)
  hipLaunchKernelGGL(attn_pool, dim3(kNtot), 256, 0, stream,
                     ent_tok, men_tok, u_f, ws_h, ws_l);

  // D4: txt = ws@Wcomb + bcomb ; img = cls_p@Wimg + bimg  (fp32 + split)
  launch_batch(2,
    GemmJob{ ws_h, ws_l, WcombT_h, WcombT_l, bcomb,
             txt_f, txt_h, txt_l, kNtot, kD, kDin, 0 },
    GemmJob{ clsp_h, clsp_l, WimgT_h, WimgT_l, bimg,
             img_f, img_h, img_l, kNtot, kD, kD, 0 });

  // D5: expert hidden layers (relu, split only)
  launch_batch(2,
    GemmJob{ txt_h, txt_l, tw1T_h, tw1T_l, moe_tb1,
             nullptr, ht_h, ht_l, kNtot, kD, kD, 1 },
    GemmJob{ img_h, img_l, iw1T_h, iw1T_l, moe_ib1,
             nullptr, hi_h, hi_l, kNtot, kD, kD, 1 });

  // D6: expert output layers (fp32 only)
  launch_batch(2,
    GemmJob{ ht_h, ht_l, tw2T_h, tw2T_l, moe_tb2,
             et_f, nullptr, nullptr, kNtot, kD, kD, 0 },
    GemmJob{ hi_h, hi_l, iw2T_h, iw2T_l, moe_ib2,
             ei_f, nullptr, nullptr, kNtot, kD, kD, 0 });

  // D7: finalize (fused moe-gate + tanh-gate + combine + LN) -> ctx (split)
  hipLaunchKernelGGL(finalize_ln, dim3(kNtot), 256, 0, stream,
                     clsp_f, et_f, ei_f, txt_f, img_f,
                     moe_gw, moe_gb, gate_w, gate_b, ln_g, ln_b, ctx_h, ctx_l);

  // D8: out = m_ctx @ e_ctx^T
  launch_batch(1,
    GemmJob{ ctx_h + (size_t)kNE * kD, ctx_l + (size_t)kNE * kD,
             ctx_h, ctx_l, nullptr,
             (float*)d_out, nullptr, nullptr, kB, kNE, kD, 0 });
}